// Round 5
// baseline (1047.252 us; speedup 1.0000x reference)
//
#include <hip/hip_runtime.h>

#define F 64
#define NCH 256          // edge chunks (= blocks) for hist/scatter passes
// buckets are 128 nodes wide: bucket = dst >> 7. N=100000 -> NB=782.
// packing: ebuf entry = src | (dst&127)<<17  (needs N < 131072)

// ---- pass A: per-chunk bucket histogram (LDS) + global degree count ----
__global__ __launch_bounds__(256) void k_hist(const int* __restrict__ dst,
                                              int* __restrict__ histM,
                                              int* __restrict__ deg,
                                              int E, int chunk, int NB) {
    extern __shared__ int h[];
    const int t = threadIdx.x;
    for (int i = t; i < NB; i += 256) h[i] = 0;
    __syncthreads();
    const int lo = blockIdx.x * chunk;
    const int hi = min(E, lo + chunk);
    for (int e = lo + t; e < hi; e += 256) {
        int d = dst[e];
        atomicAdd(&h[d >> 7], 1);
        atomicAdd(&deg[d], 1);
    }
    __syncthreads();
    // bucket-major layout: index = bucket*NCH + block
    for (int i = t; i < NB; i += 256) histM[i * NCH + blockIdx.x] = h[i];
}

// ---- generic 3-stage exclusive scan over M ints (M multiple of 1024) ----
__global__ __launch_bounds__(256) void s_part(const int* __restrict__ v,
                                              int* __restrict__ part, int M) {
    __shared__ int sd[256];
    const int t = threadIdx.x;
    const int base = blockIdx.x * 1024 + t * 4;
    int4 d = *(const int4*)&v[base];
    sd[t] = d.x + d.y + d.z + d.w;
    __syncthreads();
    for (int off = 128; off > 0; off >>= 1) {
        if (t < off) sd[t] += sd[t + off];
        __syncthreads();
    }
    if (t == 0) part[blockIdx.x] = sd[0];
}

__global__ __launch_bounds__(256) void s_scanp(int* __restrict__ part, int nb) {
    __shared__ int sums[256];
    const int t = threadIdx.x;
    int s = (t < nb) ? part[t] : 0;          // nb <= 256
    sums[t] = s;
    __syncthreads();
    for (int off = 1; off < 256; off <<= 1) {
        int v = (t >= off) ? sums[t - off] : 0;
        __syncthreads();
        sums[t] += v;
        __syncthreads();
    }
    if (t < nb) part[t] = sums[t] - s;       // exclusive
}

__global__ __launch_bounds__(256) void s_emit(int* __restrict__ v,
                                              const int* __restrict__ part, int M) {
    __shared__ int sums[256];
    const int t = threadIdx.x;
    const int base = blockIdx.x * 1024 + t * 4;
    int4 d = *(const int4*)&v[base];
    int tot = d.x + d.y + d.z + d.w;
    sums[t] = tot;
    __syncthreads();
    for (int off = 1; off < 256; off <<= 1) {
        int x = (t >= off) ? sums[t - off] : 0;
        __syncthreads();
        sums[t] += x;
        __syncthreads();
    }
    int o0 = part[blockIdx.x] + sums[t] - tot;
    int4 o;
    o.x = o0; o.y = o0 + d.x; o.z = o.y + d.y; o.w = o.z + d.z;
    *(int4*)&v[base] = o;
}

// ---- dinv = rsqrt(deg+1) ----
__global__ __launch_bounds__(256) void k_dinv(const int* __restrict__ deg,
                                              float* __restrict__ dinv, int N) {
    int i = blockIdx.x * 256 + threadIdx.x;
    if (i < N) dinv[i] = rsqrtf((float)(deg[i] + 1));
}

// ---- bucket start offsets ----
__global__ __launch_bounds__(256) void k_bstart(const int* __restrict__ scanM,
                                                int* __restrict__ bstart, int NB, int E) {
    int i = blockIdx.x * 256 + threadIdx.x;
    if (i < NB) bstart[i] = scanM[i * NCH];
    if (i == NB) bstart[NB] = E;
}

// ---- pass C: scatter packed edges into per-(bucket,block)-private regions ----
__global__ __launch_bounds__(256) void k_scatter2(const int* __restrict__ src,
                                                  const int* __restrict__ dst,
                                                  const int* __restrict__ scanM,
                                                  int* __restrict__ ebuf,
                                                  int E, int chunk, int NB) {
    extern __shared__ int cur[];
    const int t = threadIdx.x;
    for (int i = t; i < NB; i += 256) cur[i] = scanM[i * NCH + blockIdx.x];
    __syncthreads();
    const int lo = blockIdx.x * chunk;
    const int hi = min(E, lo + chunk);
    for (int e = lo + t; e < hi; e += 256) {
        int s = src[e];
        int d = dst[e];
        int p = atomicAdd(&cur[d >> 7], 1);
        ebuf[p] = s | ((d & 127) << 17);
    }
}

// ---- hs = (X @ W) * dinv[row] : 64x64 tile, 4x4/thread (round-4 tuned) ----
__global__ __launch_bounds__(256, 4) void k_gemm_scale(const float* __restrict__ X,
                                                       const float* __restrict__ W,
                                                       const float* __restrict__ dinv,
                                                       float* __restrict__ out, int N) {
    __shared__ float Ws[64 * 64];
    __shared__ float Xs[64 * 68];
    const int t = threadIdx.x;
    const int row0 = blockIdx.x * 64;

#pragma unroll
    for (int i = 0; i < 4; ++i) {
        int idx = t + i * 256;
        *(float4*)&Ws[idx * 4] = *(const float4*)&W[idx * 4];
    }
#pragma unroll
    for (int i = 0; i < 4; ++i) {
        int idx = t + i * 256;
        int r = idx >> 4, c = (idx & 15) * 4;
        int gr = row0 + r;
        float4 v = make_float4(0.f, 0.f, 0.f, 0.f);
        if (gr < N) v = *(const float4*)&X[(size_t)gr * F + c];
        *(float4*)&Xs[r * 68 + c] = v;
    }
    __syncthreads();

    const int cg = (t & 15) * 4;
    const int rg = (t >> 4) * 4;
    float acc[4][4] = {};
#pragma unroll 2
    for (int k0 = 0; k0 < 64; k0 += 4) {
        float4 xr[4];
#pragma unroll
        for (int j = 0; j < 4; ++j) xr[j] = *(const float4*)&Xs[(rg + j) * 68 + k0];
#pragma unroll
        for (int kk = 0; kk < 4; ++kk) {
            float4 w4 = *(const float4*)&Ws[(k0 + kk) * 64 + cg];
            float a0 = ((const float*)&xr[0])[kk];
            float a1 = ((const float*)&xr[1])[kk];
            float a2 = ((const float*)&xr[2])[kk];
            float a3 = ((const float*)&xr[3])[kk];
            acc[0][0] += a0 * w4.x; acc[0][1] += a0 * w4.y; acc[0][2] += a0 * w4.z; acc[0][3] += a0 * w4.w;
            acc[1][0] += a1 * w4.x; acc[1][1] += a1 * w4.y; acc[1][2] += a1 * w4.z; acc[1][3] += a1 * w4.w;
            acc[2][0] += a2 * w4.x; acc[2][1] += a2 * w4.y; acc[2][2] += a2 * w4.z; acc[2][3] += a2 * w4.w;
            acc[3][0] += a3 * w4.x; acc[3][1] += a3 * w4.y; acc[3][2] += a3 * w4.z; acc[3][3] += a3 * w4.w;
        }
    }
#pragma unroll
    for (int j = 0; j < 4; ++j) {
        int gr = row0 + rg + j;
        if (gr < N) {
            float s = dinv[gr];
            float4 v = make_float4(acc[j][0] * s, acc[j][1] * s, acc[j][2] * s, acc[j][3] * s);
            *(float4*)&out[(size_t)gr * F + cg] = v;
        }
    }
}

// ---- pass D: per-bucket LDS-accumulated aggregation, fused epilogue ----
// block = bucket (128 nodes). acc stride 65 spreads LDS banks for random locals.
__global__ __launch_bounds__(256) void k_agg2(const float* __restrict__ hs,
                                              const int* __restrict__ ebuf,
                                              const int* __restrict__ bstart,
                                              const float* __restrict__ dinv,
                                              const float* __restrict__ bias,
                                              float* __restrict__ out,
                                              int N, int do_relu) {
    __shared__ float acc[128 * 65];            // 33280 B
    const int t = threadIdx.x;
    const int bkt = blockIdx.x;
    for (int i = t; i < 128 * 65; i += 256) acc[i] = 0.f;
    __syncthreads();

    const int beg = bstart[bkt];
    const int end = bstart[bkt + 1];
    const int lane = t & 15;                   // feature float4 slice
    const int slot = t >> 4;                   // 16 edge slots

#pragma unroll 4
    for (int e = beg + slot; e < end; e += 16) {
        int pk = ebuf[e];
        int s = pk & 0x1FFFF;
        int l = pk >> 17;
        float4 v = *(const float4*)&hs[(size_t)s * F + lane * 4];
        float* ap = &acc[l * 65 + lane * 4];
        atomicAdd(ap + 0, v.x);
        atomicAdd(ap + 1, v.y);
        atomicAdd(ap + 2, v.z);
        atomicAdd(ap + 3, v.w);
    }
    __syncthreads();

    float4 bb = *(const float4*)&bias[lane * 4];
#pragma unroll
    for (int it = 0; it < 8; ++it) {
        int l = slot + it * 16;
        int node = (bkt << 7) + l;
        if (node < N) {
            float sc = dinv[node];
            const float* ap = &acc[l * 65 + lane * 4];
            float4 self = *(const float4*)&hs[(size_t)node * F + lane * 4];
            float4 o;
            o.x = (ap[0] + self.x) * sc + bb.x;
            o.y = (ap[1] + self.y) * sc + bb.y;
            o.z = (ap[2] + self.z) * sc + bb.z;
            o.w = (ap[3] + self.w) * sc + bb.w;
            if (do_relu) {
                o.x = fmaxf(o.x, 0.f); o.y = fmaxf(o.y, 0.f);
                o.z = fmaxf(o.z, 0.f); o.w = fmaxf(o.w, 0.f);
            }
            *(float4*)&out[(size_t)node * F + lane * 4] = o;
        }
    }
}

extern "C" void kernel_launch(void* const* d_in, const int* in_sizes, int n_in,
                              void* d_out, int out_size, void* d_ws, size_t ws_size,
                              hipStream_t stream) {
    const float* x  = (const float*)d_in[0];
    const int*   ei = (const int*)d_in[1];
    const float* W1 = (const float*)d_in[2];
    const float* b1 = (const float*)d_in[3];
    const float* W2 = (const float*)d_in[4];
    const float* b2 = (const float*)d_in[5];
    float* out = (float*)d_out;

    const int N = in_sizes[0] / F;
    const int E = in_sizes[1] / 2;
    const int* src = ei;
    const int* dst = ei + E;

    const int NB = (N + 127) >> 7;                       // buckets (782)
    const int chunk = (E + NCH - 1) / NCH;
    const int M  = NB * NCH;
    const int Mp = ((M + 1023) / 1024) * 1024;           // padded for scan
    const int nb2 = Mp / 1024;                           // <= 256

    // ws: deg | dinv | bstart | part2 | histM | ebuf | hs
    char* ws = (char*)d_ws;
    size_t a = 0;
    int*   deg    = (int*)(ws + a);   a += ((size_t)N * 4 + 255) & ~(size_t)255;
    float* dinv   = (float*)(ws + a); a += ((size_t)N * 4 + 255) & ~(size_t)255;
    int*   bstart = (int*)(ws + a);   a += ((size_t)(NB + 1) * 4 + 255) & ~(size_t)255;
    int*   part2  = (int*)(ws + a);   a += ((size_t)nb2 * 4 + 255) & ~(size_t)255;
    int*   histM  = (int*)(ws + a);   a += ((size_t)Mp * 4 + 255) & ~(size_t)255;
    int*   ebuf   = (int*)(ws + a);   a += ((size_t)E * 4 + 255) & ~(size_t)255;
    float* hs     = (float*)(ws + a);

    const size_t ldsNB = (size_t)NB * 4;
    const int gGemm = (N + 63) / 64;
    const int gN    = (N + 255) / 256;

    // ---- bucket partition build ----
    hipMemsetAsync(deg, 0, (size_t)N * 4, stream);
    hipMemsetAsync(histM, 0, (size_t)Mp * 4, stream);
    k_hist<<<NCH, 256, ldsNB, stream>>>(dst, histM, deg, E, chunk, NB);
    k_dinv<<<gN, 256, 0, stream>>>(deg, dinv, N);
    s_part<<<nb2, 256, 0, stream>>>(histM, part2, Mp);
    s_scanp<<<1, 256, 0, stream>>>(part2, nb2);
    s_emit<<<nb2, 256, 0, stream>>>(histM, part2, Mp);
    k_bstart<<<(NB + 256) / 256, 256, 0, stream>>>(histM, bstart, NB, E);
    k_scatter2<<<NCH, 256, ldsNB, stream>>>(src, dst, histM, ebuf, E, chunk, NB);

    // ---- layer 1 (act1 lives in d_out as scratch) ----
    k_gemm_scale<<<gGemm, 256, 0, stream>>>(x, W1, dinv, hs, N);
    k_agg2<<<NB, 256, 0, stream>>>(hs, ebuf, bstart, dinv, b1, out, N, 1);

    // ---- layer 2 ----
    k_gemm_scale<<<gGemm, 256, 0, stream>>>(out, W2, dinv, hs, N);
    k_agg2<<<NB, 256, 0, stream>>>(hs, ebuf, bstart, dinv, b2, out, N, 0);
}

// Round 6
// 237.683 us; speedup vs baseline: 4.4061x; 4.4061x over previous
//
#include <hip/hip_runtime.h>

#define F 64
#define NCH 256          // edge chunks (= blocks) for hist/scatter passes
// buckets are 128 nodes wide: bucket = dst >> 7. N=100000 -> NB=782.
// packing: ebuf entry = src | (dst&127)<<17  (needs N < 131072)

// ---- pass A: per-chunk bucket histogram (LDS only, no global atomics) ----
__global__ __launch_bounds__(256) void k_hist(const int* __restrict__ dst,
                                              int* __restrict__ histM,
                                              int E, int chunk, int NB) {
    extern __shared__ int h[];
    const int t = threadIdx.x;
    for (int i = t; i < NB; i += 256) h[i] = 0;
    __syncthreads();
    const int lo = blockIdx.x * chunk;
    const int hi = min(E, lo + chunk);
    for (int e = lo + t; e < hi; e += 256) {
        atomicAdd(&h[dst[e] >> 7], 1);
    }
    __syncthreads();
    // bucket-major layout: index = bucket*NCH + block
    for (int i = t; i < NB; i += 256) histM[i * NCH + blockIdx.x] = h[i];
}

// ---- generic 3-stage exclusive scan over M ints (M multiple of 1024) ----
__global__ __launch_bounds__(256) void s_part(const int* __restrict__ v,
                                              int* __restrict__ part, int M) {
    __shared__ int sd[256];
    const int t = threadIdx.x;
    const int base = blockIdx.x * 1024 + t * 4;
    int4 d = *(const int4*)&v[base];
    sd[t] = d.x + d.y + d.z + d.w;
    __syncthreads();
    for (int off = 128; off > 0; off >>= 1) {
        if (t < off) sd[t] += sd[t + off];
        __syncthreads();
    }
    if (t == 0) part[blockIdx.x] = sd[0];
}

__global__ __launch_bounds__(256) void s_scanp(int* __restrict__ part, int nb) {
    __shared__ int sums[256];
    const int t = threadIdx.x;
    int s = (t < nb) ? part[t] : 0;          // nb <= 256
    sums[t] = s;
    __syncthreads();
    for (int off = 1; off < 256; off <<= 1) {
        int v = (t >= off) ? sums[t - off] : 0;
        __syncthreads();
        sums[t] += v;
        __syncthreads();
    }
    if (t < nb) part[t] = sums[t] - s;       // exclusive
}

__global__ __launch_bounds__(256) void s_emit(int* __restrict__ v,
                                              const int* __restrict__ part, int M) {
    __shared__ int sums[256];
    const int t = threadIdx.x;
    const int base = blockIdx.x * 1024 + t * 4;
    int4 d = *(const int4*)&v[base];
    int tot = d.x + d.y + d.z + d.w;
    sums[t] = tot;
    __syncthreads();
    for (int off = 1; off < 256; off <<= 1) {
        int x = (t >= off) ? sums[t - off] : 0;
        __syncthreads();
        sums[t] += x;
        __syncthreads();
    }
    int o0 = part[blockIdx.x] + sums[t] - tot;
    int4 o;
    o.x = o0; o.y = o0 + d.x; o.z = o.y + d.y; o.w = o.z + d.z;
    *(int4*)&v[base] = o;
}

// ---- bucket start offsets ----
__global__ __launch_bounds__(256) void k_bstart(const int* __restrict__ scanM,
                                                int* __restrict__ bstart, int NB, int E) {
    int i = blockIdx.x * 256 + threadIdx.x;
    if (i < NB) bstart[i] = scanM[i * NCH];
    if (i == NB) bstart[NB] = E;
}

// ---- pass C: scatter packed edges into per-(bucket,block)-private regions ----
__global__ __launch_bounds__(256) void k_scatter2(const int* __restrict__ src,
                                                  const int* __restrict__ dst,
                                                  const int* __restrict__ scanM,
                                                  int* __restrict__ ebuf,
                                                  int E, int chunk, int NB) {
    extern __shared__ int cur[];
    const int t = threadIdx.x;
    for (int i = t; i < NB; i += 256) cur[i] = scanM[i * NCH + blockIdx.x];
    __syncthreads();
    const int lo = blockIdx.x * chunk;
    const int hi = min(E, lo + chunk);
    for (int e = lo + t; e < hi; e += 256) {
        int s = src[e];
        int d = dst[e];
        int p = atomicAdd(&cur[d >> 7], 1);
        ebuf[p] = s | ((d & 127) << 17);
    }
}

// ---- pass D: per-bucket LDS counting sort -> rowptr, dinv, node-sorted csr ----
// One block per bucket; all csr writes land in this block's private region.
__global__ __launch_bounds__(256) void k_csr(const int* __restrict__ ebuf,
                                             const int* __restrict__ bstart,
                                             int* __restrict__ rowptr,
                                             int* __restrict__ csr,
                                             float* __restrict__ dinv,
                                             int N, int E, int NB) {
    __shared__ int hist[128];
    __shared__ int scn[128];
    __shared__ int cur[128];
    const int t = threadIdx.x;
    const int bkt = blockIdx.x;
    const int beg = bstart[bkt];
    const int end = bstart[bkt + 1];

    if (t < 128) hist[t] = 0;
    __syncthreads();
    for (int e = beg + t; e < end; e += 256)
        atomicAdd(&hist[((unsigned)ebuf[e]) >> 17], 1);
    __syncthreads();

    // inclusive scan of 128 counts
    if (t < 128) scn[t] = hist[t];
    __syncthreads();
    for (int off = 1; off < 128; off <<= 1) {
        int v = (t < 128 && t >= off) ? scn[t - off] : 0;
        __syncthreads();
        if (t < 128) scn[t] += v;
        __syncthreads();
    }

    if (t < 128) {
        int excl = scn[t] - hist[t];
        int rp = beg + excl;
        int node = (bkt << 7) + t;
        cur[t] = rp;
        if (node < N) {
            rowptr[node] = rp;
            dinv[node] = rsqrtf((float)(hist[t] + 1));   // +1 self loop
        }
    }
    if (bkt == NB - 1 && t == 0) rowptr[N] = E;
    __syncthreads();

    for (int e = beg + t; e < end; e += 256) {
        int pk = ebuf[e];
        int p = atomicAdd(&cur[((unsigned)pk) >> 17], 1);
        csr[p] = pk & 0x1FFFF;
    }
}

// ---- hs = (X @ W) * dinv[row] : 64x64 tile, 4x4/thread (round-4 tuned) ----
__global__ __launch_bounds__(256, 4) void k_gemm_scale(const float* __restrict__ X,
                                                       const float* __restrict__ W,
                                                       const float* __restrict__ dinv,
                                                       float* __restrict__ out, int N) {
    __shared__ float Ws[64 * 64];
    __shared__ float Xs[64 * 68];
    const int t = threadIdx.x;
    const int row0 = blockIdx.x * 64;

#pragma unroll
    for (int i = 0; i < 4; ++i) {
        int idx = t + i * 256;
        *(float4*)&Ws[idx * 4] = *(const float4*)&W[idx * 4];
    }
#pragma unroll
    for (int i = 0; i < 4; ++i) {
        int idx = t + i * 256;
        int r = idx >> 4, c = (idx & 15) * 4;
        int gr = row0 + r;
        float4 v = make_float4(0.f, 0.f, 0.f, 0.f);
        if (gr < N) v = *(const float4*)&X[(size_t)gr * F + c];
        *(float4*)&Xs[r * 68 + c] = v;
    }
    __syncthreads();

    const int cg = (t & 15) * 4;
    const int rg = (t >> 4) * 4;
    float acc[4][4] = {};
#pragma unroll 2
    for (int k0 = 0; k0 < 64; k0 += 4) {
        float4 xr[4];
#pragma unroll
        for (int j = 0; j < 4; ++j) xr[j] = *(const float4*)&Xs[(rg + j) * 68 + k0];
#pragma unroll
        for (int kk = 0; kk < 4; ++kk) {
            float4 w4 = *(const float4*)&Ws[(k0 + kk) * 64 + cg];
            float a0 = ((const float*)&xr[0])[kk];
            float a1 = ((const float*)&xr[1])[kk];
            float a2 = ((const float*)&xr[2])[kk];
            float a3 = ((const float*)&xr[3])[kk];
            acc[0][0] += a0 * w4.x; acc[0][1] += a0 * w4.y; acc[0][2] += a0 * w4.z; acc[0][3] += a0 * w4.w;
            acc[1][0] += a1 * w4.x; acc[1][1] += a1 * w4.y; acc[1][2] += a1 * w4.z; acc[1][3] += a1 * w4.w;
            acc[2][0] += a2 * w4.x; acc[2][1] += a2 * w4.y; acc[2][2] += a2 * w4.z; acc[2][3] += a2 * w4.w;
            acc[3][0] += a3 * w4.x; acc[3][1] += a3 * w4.y; acc[3][2] += a3 * w4.z; acc[3][3] += a3 * w4.w;
        }
    }
#pragma unroll
    for (int j = 0; j < 4; ++j) {
        int gr = row0 + rg + j;
        if (gr < N) {
            float s = dinv[gr];
            float4 v = make_float4(acc[j][0] * s, acc[j][1] * s, acc[j][2] * s, acc[j][3] * s);
            *(float4*)&out[(size_t)gr * F + cg] = v;
        }
    }
}

// ---- fused aggregate (round-4): register accumulation, no atomics ----
__global__ __launch_bounds__(256) void k_agg(const float* __restrict__ hs,
                                             const int* __restrict__ rowptr,
                                             const int* __restrict__ csr,
                                             const float* __restrict__ dinv,
                                             const float* __restrict__ b,
                                             float* __restrict__ out,
                                             int N, int do_relu) {
    int gid = blockIdx.x * 256 + threadIdx.x;
    int node = gid >> 4;
    int lane = gid & 15;
    if (node >= N) return;
    int beg = rowptr[node];
    int end = rowptr[node + 1];
    int q = lane * 4;

    float4 acc = *(const float4*)&hs[(size_t)node * F + q];   // self loop
    for (int base = beg; base < end; base += 16) {
        int myj = base + lane;
        int myidx = (myj < end) ? csr[myj] : 0;
        int cnt = min(16, end - base);
        for (int k = 0; k < cnt; ++k) {
            int s = __shfl(myidx, k, 16);
            float4 v = *(const float4*)&hs[(size_t)s * F + q];
            acc.x += v.x; acc.y += v.y; acc.z += v.z; acc.w += v.w;
        }
    }

    float sc = dinv[node];
    float4 bb = *(const float4*)&b[q];
    float4 o = make_float4(acc.x * sc + bb.x, acc.y * sc + bb.y,
                           acc.z * sc + bb.z, acc.w * sc + bb.w);
    if (do_relu) {
        o.x = fmaxf(o.x, 0.f); o.y = fmaxf(o.y, 0.f);
        o.z = fmaxf(o.z, 0.f); o.w = fmaxf(o.w, 0.f);
    }
    *(float4*)&out[(size_t)node * F + q] = o;
}

extern "C" void kernel_launch(void* const* d_in, const int* in_sizes, int n_in,
                              void* d_out, int out_size, void* d_ws, size_t ws_size,
                              hipStream_t stream) {
    const float* x  = (const float*)d_in[0];
    const int*   ei = (const int*)d_in[1];
    const float* W1 = (const float*)d_in[2];
    const float* b1 = (const float*)d_in[3];
    const float* W2 = (const float*)d_in[4];
    const float* b2 = (const float*)d_in[5];
    float* out = (float*)d_out;

    const int N = in_sizes[0] / F;
    const int E = in_sizes[1] / 2;
    const int* src = ei;
    const int* dst = ei + E;

    const int NB = (N + 127) >> 7;                       // buckets (782)
    const int chunk = (E + NCH - 1) / NCH;
    const int M  = NB * NCH;
    const int Mp = ((M + 1023) / 1024) * 1024;           // padded for scan
    const int nb2 = Mp / 1024;                           // <= 256

    // ws: dinv | bstart | part2 | rowptr | histM | ebuf | csr | hs
    char* ws = (char*)d_ws;
    size_t a = 0;
    float* dinv   = (float*)(ws + a); a += ((size_t)N * 4 + 255) & ~(size_t)255;
    int*   bstart = (int*)(ws + a);   a += ((size_t)(NB + 1) * 4 + 255) & ~(size_t)255;
    int*   part2  = (int*)(ws + a);   a += ((size_t)nb2 * 4 + 255) & ~(size_t)255;
    int*   rowptr = (int*)(ws + a);   a += ((size_t)(N + 1) * 4 + 255) & ~(size_t)255;
    int*   histM  = (int*)(ws + a);   a += ((size_t)Mp * 4 + 255) & ~(size_t)255;
    int*   ebuf   = (int*)(ws + a);   a += ((size_t)E * 4 + 255) & ~(size_t)255;
    int*   csr    = (int*)(ws + a);   a += ((size_t)E * 4 + 255) & ~(size_t)255;
    float* hs     = (float*)(ws + a);

    const size_t ldsNB = (size_t)NB * 4;
    const int gGemm = (N + 63) / 64;
    const int gAgg  = (int)(((long long)N * 16 + 255) / 256);

    // ---- CSR build via bucket partition (no global atomics, block-private writes) ----
    hipMemsetAsync(histM, 0, (size_t)Mp * 4, stream);
    k_hist<<<NCH, 256, ldsNB, stream>>>(dst, histM, E, chunk, NB);
    s_part<<<nb2, 256, 0, stream>>>(histM, part2, Mp);
    s_scanp<<<1, 256, 0, stream>>>(part2, nb2);
    s_emit<<<nb2, 256, 0, stream>>>(histM, part2, Mp);
    k_bstart<<<(NB + 256) / 256, 256, 0, stream>>>(histM, bstart, NB, E);
    k_scatter2<<<NCH, 256, ldsNB, stream>>>(src, dst, histM, ebuf, E, chunk, NB);
    k_csr<<<NB, 256, 0, stream>>>(ebuf, bstart, rowptr, csr, dinv, N, E, NB);

    // ---- layer 1 (act1 lives in d_out as scratch) ----
    k_gemm_scale<<<gGemm, 256, 0, stream>>>(x, W1, dinv, hs, N);
    k_agg<<<gAgg, 256, 0, stream>>>(hs, rowptr, csr, dinv, b1, out, N, 1);

    // ---- layer 2 ----
    k_gemm_scale<<<gGemm, 256, 0, stream>>>(out, W2, dinv, hs, N);
    k_agg<<<gAgg, 256, 0, stream>>>(hs, rowptr, csr, dinv, b2, out, N, 0);
}

// Round 7
// 229.152 us; speedup vs baseline: 4.5701x; 1.0372x over previous
//
#include <hip/hip_runtime.h>

#define F 64
#define NCH 64           // edge chunks (= blocks) for hist/scatter passes
#define BW 256           // bucket width in nodes: bucket = dst >> 8. N=100000 -> NB=391
// packing: ebuf entry = src | (dst&255)<<17  (needs N < 131072)

static __device__ __forceinline__ unsigned short f2bf(float f) {
    unsigned u = __float_as_uint(f);
    unsigned r = (u + 0x7fffu + ((u >> 16) & 1u)) >> 16;   // RNE
    return (unsigned short)r;
}
static __device__ __forceinline__ float bflo(unsigned u) { return __uint_as_float(u << 16); }
static __device__ __forceinline__ float bfhi(unsigned u) { return __uint_as_float(u & 0xffff0000u); }

// ---- pass A: per-chunk bucket histogram (LDS only) ----
__global__ __launch_bounds__(256) void k_hist(const int* __restrict__ dst,
                                              int* __restrict__ histM,
                                              int E, int chunk, int NB) {
    extern __shared__ int h[];
    const int t = threadIdx.x;
    for (int i = t; i < NB; i += 256) h[i] = 0;
    __syncthreads();
    const int lo = blockIdx.x * chunk;
    const int hi = min(E, lo + chunk);
    for (int e = lo + t; e < hi; e += 256) {
        atomicAdd(&h[dst[e] >> 8], 1);
    }
    __syncthreads();
    for (int i = t; i < NB; i += 256) histM[i * NCH + blockIdx.x] = h[i];
}

// ---- generic 3-stage exclusive scan over M ints (M multiple of 1024) ----
__global__ __launch_bounds__(256) void s_part(const int* __restrict__ v,
                                              int* __restrict__ part, int M) {
    __shared__ int sd[256];
    const int t = threadIdx.x;
    const int base = blockIdx.x * 1024 + t * 4;
    int4 d = *(const int4*)&v[base];
    sd[t] = d.x + d.y + d.z + d.w;
    __syncthreads();
    for (int off = 128; off > 0; off >>= 1) {
        if (t < off) sd[t] += sd[t + off];
        __syncthreads();
    }
    if (t == 0) part[blockIdx.x] = sd[0];
}

__global__ __launch_bounds__(256) void s_scanp(int* __restrict__ part, int nb) {
    __shared__ int sums[256];
    const int t = threadIdx.x;
    int s = (t < nb) ? part[t] : 0;          // nb <= 256
    sums[t] = s;
    __syncthreads();
    for (int off = 1; off < 256; off <<= 1) {
        int v = (t >= off) ? sums[t - off] : 0;
        __syncthreads();
        sums[t] += v;
        __syncthreads();
    }
    if (t < nb) part[t] = sums[t] - s;       // exclusive
}

__global__ __launch_bounds__(256) void s_emit(int* __restrict__ v,
                                              const int* __restrict__ part, int M) {
    __shared__ int sums[256];
    const int t = threadIdx.x;
    const int base = blockIdx.x * 1024 + t * 4;
    int4 d = *(const int4*)&v[base];
    int tot = d.x + d.y + d.z + d.w;
    sums[t] = tot;
    __syncthreads();
    for (int off = 1; off < 256; off <<= 1) {
        int x = (t >= off) ? sums[t - off] : 0;
        __syncthreads();
        sums[t] += x;
        __syncthreads();
    }
    int o0 = part[blockIdx.x] + sums[t] - tot;
    int4 o;
    o.x = o0; o.y = o0 + d.x; o.z = o.y + d.y; o.w = o.z + d.z;
    *(int4*)&v[base] = o;
}

// ---- bucket start offsets ----
__global__ __launch_bounds__(256) void k_bstart(const int* __restrict__ scanM,
                                                int* __restrict__ bstart, int NB, int E) {
    int i = blockIdx.x * 256 + threadIdx.x;
    if (i < NB) bstart[i] = scanM[i * NCH];
    if (i == NB) bstart[NB] = E;
}

// ---- pass C: scatter packed edges into per-(bucket,block)-private regions ----
__global__ __launch_bounds__(256) void k_scatter2(const int* __restrict__ src,
                                                  const int* __restrict__ dst,
                                                  const int* __restrict__ scanM,
                                                  int* __restrict__ ebuf,
                                                  int E, int chunk, int NB) {
    extern __shared__ int cur[];
    const int t = threadIdx.x;
    for (int i = t; i < NB; i += 256) cur[i] = scanM[i * NCH + blockIdx.x];
    __syncthreads();
    const int lo = blockIdx.x * chunk;
    const int hi = min(E, lo + chunk);
    for (int e = lo + t; e < hi; e += 256) {
        int s = src[e];
        int d = dst[e];
        int p = atomicAdd(&cur[d >> 8], 1);
        ebuf[p] = s | ((d & 255) << 17);
    }
}

// ---- pass D: per-bucket LDS counting sort -> rowptr, dinv, node-sorted csr ----
__global__ __launch_bounds__(256) void k_csr(const int* __restrict__ ebuf,
                                             const int* __restrict__ bstart,
                                             int* __restrict__ rowptr,
                                             int* __restrict__ csr,
                                             float* __restrict__ dinv,
                                             int N, int E, int NB) {
    __shared__ int hist[256];
    __shared__ int scn[256];
    __shared__ int cur[256];
    const int t = threadIdx.x;
    const int bkt = blockIdx.x;
    const int beg = bstart[bkt];
    const int end = bstart[bkt + 1];

    hist[t] = 0;
    __syncthreads();
    for (int e = beg + t; e < end; e += 256)
        atomicAdd(&hist[((unsigned)ebuf[e]) >> 17], 1);
    __syncthreads();

    // inclusive scan of 256 counts
    scn[t] = hist[t];
    __syncthreads();
    for (int off = 1; off < 256; off <<= 1) {
        int v = (t >= off) ? scn[t - off] : 0;
        __syncthreads();
        scn[t] += v;
        __syncthreads();
    }

    {
        int excl = scn[t] - hist[t];
        int rp = beg + excl;
        int node = (bkt << 8) + t;
        cur[t] = rp;
        if (node < N) {
            rowptr[node] = rp;
            dinv[node] = rsqrtf((float)(hist[t] + 1));   // +1 self loop
        }
    }
    if (bkt == NB - 1 && t == 0) rowptr[N] = E;
    __syncthreads();

    for (int e = beg + t; e < end; e += 256) {
        int pk = ebuf[e];
        int p = atomicAdd(&cur[((unsigned)pk) >> 17], 1);
        csr[p] = pk & 0x1FFFF;
    }
}

// ---- hs(bf16) = (X @ W) * dinv[row] : 64x64 tile, 4x4/thread ----
__global__ __launch_bounds__(256, 4) void k_gemm_scale(const float* __restrict__ X,
                                                       const float* __restrict__ W,
                                                       const float* __restrict__ dinv,
                                                       unsigned short* __restrict__ out, int N) {
    __shared__ float Ws[64 * 64];
    __shared__ float Xs[64 * 68];
    const int t = threadIdx.x;
    const int row0 = blockIdx.x * 64;

#pragma unroll
    for (int i = 0; i < 4; ++i) {
        int idx = t + i * 256;
        *(float4*)&Ws[idx * 4] = *(const float4*)&W[idx * 4];
    }
#pragma unroll
    for (int i = 0; i < 4; ++i) {
        int idx = t + i * 256;
        int r = idx >> 4, c = (idx & 15) * 4;
        int gr = row0 + r;
        float4 v = make_float4(0.f, 0.f, 0.f, 0.f);
        if (gr < N) v = *(const float4*)&X[(size_t)gr * F + c];
        *(float4*)&Xs[r * 68 + c] = v;
    }
    __syncthreads();

    const int cg = (t & 15) * 4;
    const int rg = (t >> 4) * 4;
    float acc[4][4] = {};
#pragma unroll 2
    for (int k0 = 0; k0 < 64; k0 += 4) {
        float4 xr[4];
#pragma unroll
        for (int j = 0; j < 4; ++j) xr[j] = *(const float4*)&Xs[(rg + j) * 68 + k0];
#pragma unroll
        for (int kk = 0; kk < 4; ++kk) {
            float4 w4 = *(const float4*)&Ws[(k0 + kk) * 64 + cg];
            float a0 = ((const float*)&xr[0])[kk];
            float a1 = ((const float*)&xr[1])[kk];
            float a2 = ((const float*)&xr[2])[kk];
            float a3 = ((const float*)&xr[3])[kk];
            acc[0][0] += a0 * w4.x; acc[0][1] += a0 * w4.y; acc[0][2] += a0 * w4.z; acc[0][3] += a0 * w4.w;
            acc[1][0] += a1 * w4.x; acc[1][1] += a1 * w4.y; acc[1][2] += a1 * w4.z; acc[1][3] += a1 * w4.w;
            acc[2][0] += a2 * w4.x; acc[2][1] += a2 * w4.y; acc[2][2] += a2 * w4.z; acc[2][3] += a2 * w4.w;
            acc[3][0] += a3 * w4.x; acc[3][1] += a3 * w4.y; acc[3][2] += a3 * w4.z; acc[3][3] += a3 * w4.w;
        }
    }
#pragma unroll
    for (int j = 0; j < 4; ++j) {
        int gr = row0 + rg + j;
        if (gr < N) {
            float s = dinv[gr];
            uint2 pk;
            pk.x = (unsigned)f2bf(acc[j][0] * s) | ((unsigned)f2bf(acc[j][1] * s) << 16);
            pk.y = (unsigned)f2bf(acc[j][2] * s) | ((unsigned)f2bf(acc[j][3] * s) << 16);
            *(uint2*)&out[(size_t)gr * F + cg] = pk;
        }
    }
}

// ---- fused aggregate: register accumulation over bf16 rows, 8 lanes/node ----
__global__ __launch_bounds__(256) void k_agg(const unsigned short* __restrict__ hs,
                                             const int* __restrict__ rowptr,
                                             const int* __restrict__ csr,
                                             const float* __restrict__ dinv,
                                             const float* __restrict__ b,
                                             float* __restrict__ out,
                                             int N, int do_relu) {
    int gid = blockIdx.x * 256 + threadIdx.x;
    int node = gid >> 3;
    int lane = gid & 7;
    if (node >= N) return;
    int beg = rowptr[node];
    int end = rowptr[node + 1];
    const int q = lane * 8;                   // 8 bf16 features per lane

    float acc0, acc1, acc2, acc3, acc4, acc5, acc6, acc7;
    {
        uint4 u = *(const uint4*)&hs[(size_t)node * F + q];   // self loop
        acc0 = bflo(u.x); acc1 = bfhi(u.x);
        acc2 = bflo(u.y); acc3 = bfhi(u.y);
        acc4 = bflo(u.z); acc5 = bfhi(u.z);
        acc6 = bflo(u.w); acc7 = bfhi(u.w);
    }
    for (int base = beg; base < end; base += 8) {
        int myj = base + lane;
        int myidx = (myj < end) ? csr[myj] : 0;
        int cnt = min(8, end - base);
        for (int k = 0; k < cnt; ++k) {
            int s = __shfl(myidx, k, 8);
            uint4 u = *(const uint4*)&hs[(size_t)s * F + q];
            acc0 += bflo(u.x); acc1 += bfhi(u.x);
            acc2 += bflo(u.y); acc3 += bfhi(u.y);
            acc4 += bflo(u.z); acc5 += bfhi(u.z);
            acc6 += bflo(u.w); acc7 += bfhi(u.w);
        }
    }

    float sc = dinv[node];
    float4 b0 = *(const float4*)&b[q];
    float4 b1 = *(const float4*)&b[q + 4];
    float4 o0 = make_float4(acc0 * sc + b0.x, acc1 * sc + b0.y,
                            acc2 * sc + b0.z, acc3 * sc + b0.w);
    float4 o1 = make_float4(acc4 * sc + b1.x, acc5 * sc + b1.y,
                            acc6 * sc + b1.z, acc7 * sc + b1.w);
    if (do_relu) {
        o0.x = fmaxf(o0.x, 0.f); o0.y = fmaxf(o0.y, 0.f);
        o0.z = fmaxf(o0.z, 0.f); o0.w = fmaxf(o0.w, 0.f);
        o1.x = fmaxf(o1.x, 0.f); o1.y = fmaxf(o1.y, 0.f);
        o1.z = fmaxf(o1.z, 0.f); o1.w = fmaxf(o1.w, 0.f);
    }
    *(float4*)&out[(size_t)node * F + q] = o0;
    *(float4*)&out[(size_t)node * F + q + 4] = o1;
}

extern "C" void kernel_launch(void* const* d_in, const int* in_sizes, int n_in,
                              void* d_out, int out_size, void* d_ws, size_t ws_size,
                              hipStream_t stream) {
    const float* x  = (const float*)d_in[0];
    const int*   ei = (const int*)d_in[1];
    const float* W1 = (const float*)d_in[2];
    const float* b1 = (const float*)d_in[3];
    const float* W2 = (const float*)d_in[4];
    const float* b2 = (const float*)d_in[5];
    float* out = (float*)d_out;

    const int N = in_sizes[0] / F;
    const int E = in_sizes[1] / 2;
    const int* src = ei;
    const int* dst = ei + E;

    const int NB = (N + BW - 1) >> 8;                    // buckets (391)
    const int chunk = (E + NCH - 1) / NCH;
    const int M  = NB * NCH;
    const int Mp = ((M + 1023) / 1024) * 1024;           // padded for scan
    const int nb2 = Mp / 1024;                           // <= 256

    // ws: dinv | bstart | part2 | rowptr | histM | ebuf | csr | hs(bf16)
    char* ws = (char*)d_ws;
    size_t a = 0;
    float* dinv   = (float*)(ws + a); a += ((size_t)N * 4 + 255) & ~(size_t)255;
    int*   bstart = (int*)(ws + a);   a += ((size_t)(NB + 1) * 4 + 255) & ~(size_t)255;
    int*   part2  = (int*)(ws + a);   a += ((size_t)nb2 * 4 + 255) & ~(size_t)255;
    int*   rowptr = (int*)(ws + a);   a += ((size_t)(N + 1) * 4 + 255) & ~(size_t)255;
    int*   histM  = (int*)(ws + a);   a += ((size_t)Mp * 4 + 255) & ~(size_t)255;
    int*   ebuf   = (int*)(ws + a);   a += ((size_t)E * 4 + 255) & ~(size_t)255;
    int*   csr    = (int*)(ws + a);   a += ((size_t)E * 4 + 255) & ~(size_t)255;
    unsigned short* hs = (unsigned short*)(ws + a);

    const size_t ldsNB = (size_t)NB * 4;
    const int gGemm = (N + 63) / 64;
    const int gAgg  = (int)(((long long)N * 8 + 255) / 256);

    // ---- CSR build via bucket partition ----
    hipMemsetAsync(histM, 0, (size_t)Mp * 4, stream);
    k_hist<<<NCH, 256, ldsNB, stream>>>(dst, histM, E, chunk, NB);
    s_part<<<nb2, 256, 0, stream>>>(histM, part2, Mp);
    s_scanp<<<1, 256, 0, stream>>>(part2, nb2);
    s_emit<<<nb2, 256, 0, stream>>>(histM, part2, Mp);
    k_bstart<<<(NB + 256) / 256, 256, 0, stream>>>(histM, bstart, NB, E);
    k_scatter2<<<NCH, 256, ldsNB, stream>>>(src, dst, histM, ebuf, E, chunk, NB);
    k_csr<<<NB, 256, 0, stream>>>(ebuf, bstart, rowptr, csr, dinv, N, E, NB);

    // ---- layer 1 (act1 fp32 lives in d_out as scratch) ----
    k_gemm_scale<<<gGemm, 256, 0, stream>>>(x, W1, dinv, hs, N);
    k_agg<<<gAgg, 256, 0, stream>>>(hs, rowptr, csr, dinv, b1, out, N, 1);

    // ---- layer 2 ----
    k_gemm_scale<<<gGemm, 256, 0, stream>>>(out, W2, dinv, hs, N);
    k_agg<<<gAgg, 256, 0, stream>>>(hs, rowptr, csr, dinv, b2, out, N, 0);
}

// Round 8
// 205.883 us; speedup vs baseline: 5.0866x; 1.1130x over previous
//
#include <hip/hip_runtime.h>

#define F 64
#define NCH 64           // edge chunks (= blocks) for hist/scatter passes
// buckets are 256 nodes wide: bucket = dst >> 8. N=100000 -> NB=391
// packing: ebuf entry = src | (dst&255)<<17  (needs N < 131072)

typedef __attribute__((ext_vector_type(8))) short bf16x8;
typedef __attribute__((ext_vector_type(4))) float f32x4;

static __device__ __forceinline__ unsigned short f2bf(float f) {
    unsigned u = __float_as_uint(f);
    return (unsigned short)((u + 0x7fffu + ((u >> 16) & 1u)) >> 16);   // RNE
}
static __device__ __forceinline__ float bflo(unsigned u) { return __uint_as_float(u << 16); }
static __device__ __forceinline__ float bfhi(unsigned u) { return __uint_as_float(u & 0xffff0000u); }

// ---- pass A: per-chunk bucket histogram (LDS only) ----
__global__ __launch_bounds__(256) void k_hist(const int* __restrict__ dst,
                                              int* __restrict__ histM,
                                              int E, int chunk, int NB) {
    extern __shared__ int h[];
    const int t = threadIdx.x;
    for (int i = t; i < NB; i += 256) h[i] = 0;
    __syncthreads();
    const int lo = blockIdx.x * chunk;
    const int hi = min(E, lo + chunk);
    for (int e = lo + t; e < hi; e += 256) {
        atomicAdd(&h[dst[e] >> 8], 1);
    }
    __syncthreads();
    for (int i = t; i < NB; i += 256) histM[i * NCH + blockIdx.x] = h[i];
}

// ---- generic 3-stage exclusive scan over M ints (M multiple of 1024) ----
__global__ __launch_bounds__(256) void s_part(const int* __restrict__ v,
                                              int* __restrict__ part, int M) {
    __shared__ int sd[256];
    const int t = threadIdx.x;
    const int base = blockIdx.x * 1024 + t * 4;
    int4 d = *(const int4*)&v[base];
    sd[t] = d.x + d.y + d.z + d.w;
    __syncthreads();
    for (int off = 128; off > 0; off >>= 1) {
        if (t < off) sd[t] += sd[t + off];
        __syncthreads();
    }
    if (t == 0) part[blockIdx.x] = sd[0];
}

__global__ __launch_bounds__(256) void s_scanp(int* __restrict__ part, int nb) {
    __shared__ int sums[256];
    const int t = threadIdx.x;
    int s = (t < nb) ? part[t] : 0;          // nb <= 256
    sums[t] = s;
    __syncthreads();
    for (int off = 1; off < 256; off <<= 1) {
        int v = (t >= off) ? sums[t - off] : 0;
        __syncthreads();
        sums[t] += v;
        __syncthreads();
    }
    if (t < nb) part[t] = sums[t] - s;       // exclusive
}

__global__ __launch_bounds__(256) void s_emit(int* __restrict__ v,
                                              const int* __restrict__ part, int M) {
    __shared__ int sums[256];
    const int t = threadIdx.x;
    const int base = blockIdx.x * 1024 + t * 4;
    int4 d = *(const int4*)&v[base];
    int tot = d.x + d.y + d.z + d.w;
    sums[t] = tot;
    __syncthreads();
    for (int off = 1; off < 256; off <<= 1) {
        int x = (t >= off) ? sums[t - off] : 0;
        __syncthreads();
        sums[t] += x;
        __syncthreads();
    }
    int o0 = part[blockIdx.x] + sums[t] - tot;
    int4 o;
    o.x = o0; o.y = o0 + d.x; o.z = o.y + d.y; o.w = o.z + d.z;
    *(int4*)&v[base] = o;
}

// ---- pass C: scatter packed edges into per-(bucket,block)-private regions ----
__global__ __launch_bounds__(256) void k_scatter2(const int* __restrict__ src,
                                                  const int* __restrict__ dst,
                                                  const int* __restrict__ scanM,
                                                  int* __restrict__ ebuf,
                                                  int E, int chunk, int NB) {
    extern __shared__ int cur[];
    const int t = threadIdx.x;
    for (int i = t; i < NB; i += 256) cur[i] = scanM[i * NCH + blockIdx.x];
    __syncthreads();
    const int lo = blockIdx.x * chunk;
    const int hi = min(E, lo + chunk);
    for (int e = lo + t; e < hi; e += 256) {
        int s = src[e];
        int d = dst[e];
        int p = atomicAdd(&cur[d >> 8], 1);
        ebuf[p] = s | ((d & 255) << 17);
    }
}

// ---- pass D: per-bucket LDS counting sort -> rowptr, dinv, node-sorted csr ----
// bstart folded in: beg/end read straight from scanM (bucket-major, column 0).
__global__ __launch_bounds__(256) void k_csr(const int* __restrict__ ebuf,
                                             const int* __restrict__ scanM,
                                             int* __restrict__ rowptr,
                                             int* __restrict__ csr,
                                             float* __restrict__ dinv,
                                             int N, int E, int NB) {
    __shared__ int hist[256];
    __shared__ int scn[256];
    __shared__ int cur[256];
    const int t = threadIdx.x;
    const int bkt = blockIdx.x;
    const int beg = scanM[bkt * NCH];
    const int end = (bkt + 1 < NB) ? scanM[(bkt + 1) * NCH] : E;

    hist[t] = 0;
    __syncthreads();
    for (int e = beg + t; e < end; e += 256)
        atomicAdd(&hist[((unsigned)ebuf[e]) >> 17], 1);
    __syncthreads();

    scn[t] = hist[t];
    __syncthreads();
    for (int off = 1; off < 256; off <<= 1) {
        int v = (t >= off) ? scn[t - off] : 0;
        __syncthreads();
        scn[t] += v;
        __syncthreads();
    }

    {
        int excl = scn[t] - hist[t];
        int rp = beg + excl;
        int node = (bkt << 8) + t;
        cur[t] = rp;
        if (node < N) {
            rowptr[node] = rp;
            dinv[node] = rsqrtf((float)(hist[t] + 1));   // +1 self loop
        }
    }
    if (bkt == NB - 1 && t == 0) rowptr[N] = E;
    __syncthreads();

    for (int e = beg + t; e < end; e += 256) {
        int pk = ebuf[e];
        int p = atomicAdd(&cur[((unsigned)pk) >> 17], 1);
        csr[p] = pk & 0x1FFFF;
    }
}

// ---- hs(bf16) = (X @ W) * dinv[row] via MFMA ----
// 64x64 tile / block, 4 waves; wave w owns rows w*16..w*16+15 (4 col-tiles).
// A[m=lane&15][k=quad*8+j]; B[k=quad*8+j][n=lane&15]; D: col=lane&15, row=quad*4+reg.
__global__ __launch_bounds__(256) void k_gemm_mfma(const float* __restrict__ X,
                                                   const float* __restrict__ W,
                                                   const float* __restrict__ dinv,
                                                   unsigned short* __restrict__ hs, int N) {
    __shared__ unsigned short Wt[64 * 72];   // W transposed: Wt[n][k], stride 72 (pad)
    __shared__ unsigned short Xs[64 * 72];   // X tile:       Xs[r][k], stride 72
    const int t = threadIdx.x;
    const int row0 = blockIdx.x * 64;

    // stage W -> bf16, transposed
#pragma unroll
    for (int i = 0; i < 16; ++i) {
        int e = t + i * 256;
        int k = e >> 6, n = e & 63;
        Wt[n * 72 + k] = f2bf(W[e]);
    }
    // stage X tile -> bf16
#pragma unroll
    for (int i = 0; i < 4; ++i) {
        int idx = t + i * 256;
        int r = idx >> 4, c = (idx & 15) * 4;
        int gr = row0 + r;
        float4 v = make_float4(0.f, 0.f, 0.f, 0.f);
        if (gr < N) v = *(const float4*)&X[(size_t)gr * F + c];
        unsigned p0 = (unsigned)f2bf(v.x) | ((unsigned)f2bf(v.y) << 16);
        unsigned p1 = (unsigned)f2bf(v.z) | ((unsigned)f2bf(v.w) << 16);
        *(uint2*)&Xs[r * 72 + c] = make_uint2(p0, p1);
    }
    __syncthreads();

    const int w    = t >> 6;
    const int lane = t & 63;
    const int l15  = lane & 15;
    const int quad = lane >> 4;

    // B fragments (block-constant): 4 col-tiles x 2 K-halves
    bf16x8 bf[4][2];
#pragma unroll
    for (int ct = 0; ct < 4; ++ct)
#pragma unroll
        for (int kc = 0; kc < 2; ++kc)
            bf[ct][kc] = *(const bf16x8*)&Wt[(ct * 16 + l15) * 72 + kc * 32 + quad * 8];

    // A fragments for this wave's 16 rows
    const int am = w * 16 + l15;
    bf16x8 af0 = *(const bf16x8*)&Xs[am * 72 + quad * 8];
    bf16x8 af1 = *(const bf16x8*)&Xs[am * 72 + 32 + quad * 8];

    f32x4 acc[4];
#pragma unroll
    for (int ct = 0; ct < 4; ++ct) {
        f32x4 z = {0.f, 0.f, 0.f, 0.f};
        z = __builtin_amdgcn_mfma_f32_16x16x32_bf16(af0, bf[ct][0], z, 0, 0, 0);
        z = __builtin_amdgcn_mfma_f32_16x16x32_bf16(af1, bf[ct][1], z, 0, 0, 0);
        acc[ct] = z;
    }

    float dv[4];
#pragma unroll
    for (int r = 0; r < 4; ++r) {
        int row = row0 + w * 16 + quad * 4 + r;
        dv[r] = (row < N) ? dinv[row] : 0.f;
    }
#pragma unroll
    for (int ct = 0; ct < 4; ++ct) {
#pragma unroll
        for (int r = 0; r < 4; ++r) {
            int row = row0 + w * 16 + quad * 4 + r;
            if (row < N)
                hs[(size_t)row * F + ct * 16 + l15] = f2bf(acc[ct][r] * dv[r]);
        }
    }
}

// ---- fused aggregate: 16-deep batched gathers for MLP, register accumulate ----
__global__ __launch_bounds__(256) void k_agg(const unsigned short* __restrict__ hs,
                                             const int* __restrict__ rowptr,
                                             const int* __restrict__ csr,
                                             const float* __restrict__ dinv,
                                             const float* __restrict__ b,
                                             float* __restrict__ out,
                                             int N, int do_relu) {
    int gid = blockIdx.x * 256 + threadIdx.x;
    int node = gid >> 3;
    int lane = gid & 7;
    if (node >= N) return;
    int beg = rowptr[node];
    int end = rowptr[node + 1];
    const int q = lane * 8;                       // 8 bf16 features per lane
    const uint4* hsb = (const uint4*)hs;          // row = 8 uint4

    float acc0, acc1, acc2, acc3, acc4, acc5, acc6, acc7;
    {
        uint4 u = hsb[(size_t)node * 8 + lane];   // self loop
        acc0 = bflo(u.x); acc1 = bfhi(u.x);
        acc2 = bflo(u.y); acc3 = bfhi(u.y);
        acc4 = bflo(u.z); acc5 = bfhi(u.z);
        acc6 = bflo(u.w); acc7 = bfhi(u.w);
    }

    for (int base = beg; base < end; base += 16) {
        int i0 = base + lane;
        int i1 = base + 8 + lane;
        int x0 = (i0 < end) ? csr[i0] : 0;        // row 0 fallback: L2-hot, discarded
        int x1 = (i1 < end) ? csr[i1] : 0;
        uint4 r[16];
#pragma unroll
        for (int k = 0; k < 8; ++k) {
            int s = __shfl(x0, k, 8);
            r[k] = hsb[(size_t)s * 8 + lane];
        }
#pragma unroll
        for (int k = 0; k < 8; ++k) {
            int s = __shfl(x1, k, 8);
            r[8 + k] = hsb[(size_t)s * 8 + lane];
        }
        int cnt = min(16, end - base);
#pragma unroll
        for (int k = 0; k < 16; ++k) {
            if (k < cnt) {
                uint4 u = r[k];
                acc0 += bflo(u.x); acc1 += bfhi(u.x);
                acc2 += bflo(u.y); acc3 += bfhi(u.y);
                acc4 += bflo(u.z); acc5 += bfhi(u.z);
                acc6 += bflo(u.w); acc7 += bfhi(u.w);
            }
        }
    }

    float sc = dinv[node];
    float4 b0 = *(const float4*)&b[q];
    float4 b1 = *(const float4*)&b[q + 4];
    float4 o0 = make_float4(acc0 * sc + b0.x, acc1 * sc + b0.y,
                            acc2 * sc + b0.z, acc3 * sc + b0.w);
    float4 o1 = make_float4(acc4 * sc + b1.x, acc5 * sc + b1.y,
                            acc6 * sc + b1.z, acc7 * sc + b1.w);
    if (do_relu) {
        o0.x = fmaxf(o0.x, 0.f); o0.y = fmaxf(o0.y, 0.f);
        o0.z = fmaxf(o0.z, 0.f); o0.w = fmaxf(o0.w, 0.f);
        o1.x = fmaxf(o1.x, 0.f); o1.y = fmaxf(o1.y, 0.f);
        o1.z = fmaxf(o1.z, 0.f); o1.w = fmaxf(o1.w, 0.f);
    }
    *(float4*)&out[(size_t)node * F + q] = o0;
    *(float4*)&out[(size_t)node * F + q + 4] = o1;
}

extern "C" void kernel_launch(void* const* d_in, const int* in_sizes, int n_in,
                              void* d_out, int out_size, void* d_ws, size_t ws_size,
                              hipStream_t stream) {
    const float* x  = (const float*)d_in[0];
    const int*   ei = (const int*)d_in[1];
    const float* W1 = (const float*)d_in[2];
    const float* b1 = (const float*)d_in[3];
    const float* W2 = (const float*)d_in[4];
    const float* b2 = (const float*)d_in[5];
    float* out = (float*)d_out;

    const int N = in_sizes[0] / F;
    const int E = in_sizes[1] / 2;
    const int* src = ei;
    const int* dst = ei + E;

    const int NB = (N + 255) >> 8;                       // buckets (391)
    const int chunk = (E + NCH - 1) / NCH;
    const int M  = NB * NCH;
    const int Mp = ((M + 1023) / 1024) * 1024;           // padded for scan
    const int nb2 = Mp / 1024;                           // <= 256

    // ws: dinv | part2 | rowptr | histM | ebuf | csr | hs(bf16)
    char* ws = (char*)d_ws;
    size_t a = 0;
    float* dinv   = (float*)(ws + a); a += ((size_t)N * 4 + 255) & ~(size_t)255;
    int*   part2  = (int*)(ws + a);   a += ((size_t)nb2 * 4 + 255) & ~(size_t)255;
    int*   rowptr = (int*)(ws + a);   a += ((size_t)(N + 1) * 4 + 255) & ~(size_t)255;
    int*   histM  = (int*)(ws + a);   a += ((size_t)Mp * 4 + 255) & ~(size_t)255;
    int*   ebuf   = (int*)(ws + a);   a += ((size_t)E * 4 + 255) & ~(size_t)255;
    int*   csr    = (int*)(ws + a);   a += ((size_t)E * 4 + 255) & ~(size_t)255;
    unsigned short* hs = (unsigned short*)(ws + a);

    const size_t ldsNB = (size_t)NB * 4;
    const int gGemm = (N + 63) / 64;
    const int gAgg  = (int)(((long long)N * 8 + 255) / 256);

    // ---- CSR build via bucket partition ----
    hipMemsetAsync(histM, 0, (size_t)Mp * 4, stream);
    k_hist<<<NCH, 256, ldsNB, stream>>>(dst, histM, E, chunk, NB);
    s_part<<<nb2, 256, 0, stream>>>(histM, part2, Mp);
    s_scanp<<<1, 256, 0, stream>>>(part2, nb2);
    s_emit<<<nb2, 256, 0, stream>>>(histM, part2, Mp);
    k_scatter2<<<NCH, 256, ldsNB, stream>>>(src, dst, histM, ebuf, E, chunk, NB);
    k_csr<<<NB, 256, 0, stream>>>(ebuf, histM, rowptr, csr, dinv, N, E, NB);

    // ---- layer 1 (act1 fp32 lives in d_out as scratch) ----
    k_gemm_mfma<<<gGemm, 256, 0, stream>>>(x, W1, dinv, hs, N);
    k_agg<<<gAgg, 256, 0, stream>>>(hs, rowptr, csr, dinv, b1, out, N, 1);

    // ---- layer 2 ----
    k_gemm_mfma<<<gGemm, 256, 0, stream>>>(out, W2, dinv, hs, N);
    k_agg<<<gAgg, 256, 0, stream>>>(hs, rowptr, csr, dinv, b2, out, N, 0);
}

// Round 9
// 198.307 us; speedup vs baseline: 5.2810x; 1.0382x over previous
//
#include <hip/hip_runtime.h>

#define F 64
#define NCH 64           // edge chunks (= blocks) for hist/scatter passes
// buckets are 256 nodes wide: bucket = dst >> 8. N=100000 -> NB=391
// packing: ebuf entry = src | (dst&255)<<17  (needs N < 131072)

typedef __attribute__((ext_vector_type(8))) short bf16x8;
typedef __attribute__((ext_vector_type(4))) float f32x4;

static __device__ __forceinline__ unsigned short f2bf(float f) {
    unsigned u = __float_as_uint(f);
    return (unsigned short)((u + 0x7fffu + ((u >> 16) & 1u)) >> 16);   // RNE
}
static __device__ __forceinline__ float bflo(unsigned u) { return __uint_as_float(u << 16); }
static __device__ __forceinline__ float bfhi(unsigned u) { return __uint_as_float(u & 0xffff0000u); }

// ---- W1/W2 -> bf16 transposed [n*64+k] (once per launch) ----
__global__ __launch_bounds__(256) void k_prep(const float* __restrict__ W1,
                                              const float* __restrict__ W2,
                                              unsigned short* __restrict__ W1t,
                                              unsigned short* __restrict__ W2t) {
    const float* W = blockIdx.x ? W2 : W1;
    unsigned short* Wt = blockIdx.x ? W2t : W1t;
    const int t = threadIdx.x;
#pragma unroll
    for (int i = 0; i < 16; ++i) {
        int e = t + i * 256;            // e = n*64+k
        int n = e >> 6, k = e & 63;
        Wt[e] = f2bf(W[k * 64 + n]);
    }
}

// ---- pass A: per-chunk bucket histogram (LDS only) ----
__global__ __launch_bounds__(256) void k_hist(const int* __restrict__ dst,
                                              int* __restrict__ histM,
                                              int E, int chunk, int NB) {
    extern __shared__ int h[];
    const int t = threadIdx.x;
    for (int i = t; i < NB; i += 256) h[i] = 0;
    __syncthreads();
    const int lo = blockIdx.x * chunk;
    const int hi = min(E, lo + chunk);
    for (int e = lo + t; e < hi; e += 256) {
        atomicAdd(&h[dst[e] >> 8], 1);
    }
    __syncthreads();
    for (int i = t; i < NB; i += 256) histM[i * NCH + blockIdx.x] = h[i];
}

// ---- generic 3-stage exclusive scan over M ints (M multiple of 1024) ----
__global__ __launch_bounds__(256) void s_part(const int* __restrict__ v,
                                              int* __restrict__ part, int M) {
    __shared__ int sd[256];
    const int t = threadIdx.x;
    const int base = blockIdx.x * 1024 + t * 4;
    int4 d = *(const int4*)&v[base];
    sd[t] = d.x + d.y + d.z + d.w;
    __syncthreads();
    for (int off = 128; off > 0; off >>= 1) {
        if (t < off) sd[t] += sd[t + off];
        __syncthreads();
    }
    if (t == 0) part[blockIdx.x] = sd[0];
}

__global__ __launch_bounds__(256) void s_scanp(int* __restrict__ part, int nb) {
    __shared__ int sums[256];
    const int t = threadIdx.x;
    int s = (t < nb) ? part[t] : 0;          // nb <= 256
    sums[t] = s;
    __syncthreads();
    for (int off = 1; off < 256; off <<= 1) {
        int v = (t >= off) ? sums[t - off] : 0;
        __syncthreads();
        sums[t] += v;
        __syncthreads();
    }
    if (t < nb) part[t] = sums[t] - s;       // exclusive
}

__global__ __launch_bounds__(256) void s_emit(int* __restrict__ v,
                                              const int* __restrict__ part, int M) {
    __shared__ int sums[256];
    const int t = threadIdx.x;
    const int base = blockIdx.x * 1024 + t * 4;
    int4 d = *(const int4*)&v[base];
    int tot = d.x + d.y + d.z + d.w;
    sums[t] = tot;
    __syncthreads();
    for (int off = 1; off < 256; off <<= 1) {
        int x = (t >= off) ? sums[t - off] : 0;
        __syncthreads();
        sums[t] += x;
        __syncthreads();
    }
    int o0 = part[blockIdx.x] + sums[t] - tot;
    int4 o;
    o.x = o0; o.y = o0 + d.x; o.z = o.y + d.y; o.w = o.z + d.z;
    *(int4*)&v[base] = o;
}

// ---- pass C: scatter packed edges into per-(bucket,block)-private regions ----
__global__ __launch_bounds__(256) void k_scatter2(const int* __restrict__ src,
                                                  const int* __restrict__ dst,
                                                  const int* __restrict__ scanM,
                                                  int* __restrict__ ebuf,
                                                  int E, int chunk, int NB) {
    extern __shared__ int cur[];
    const int t = threadIdx.x;
    for (int i = t; i < NB; i += 256) cur[i] = scanM[i * NCH + blockIdx.x];
    __syncthreads();
    const int lo = blockIdx.x * chunk;
    const int hi = min(E, lo + chunk);
    for (int e = lo + t; e < hi; e += 256) {
        int s = src[e];
        int d = dst[e];
        int p = atomicAdd(&cur[d >> 8], 1);
        ebuf[p] = s | ((d & 255) << 17);
    }
}

// ---- pass D: per-bucket LDS counting sort -> rowptr, dinv, node-sorted csr ----
__global__ __launch_bounds__(256) void k_csr(const int* __restrict__ ebuf,
                                             const int* __restrict__ scanM,
                                             int* __restrict__ rowptr,
                                             int* __restrict__ csr,
                                             float* __restrict__ dinv,
                                             int N, int E, int NB) {
    __shared__ int hist[256];
    __shared__ int scn[256];
    __shared__ int cur[256];
    const int t = threadIdx.x;
    const int bkt = blockIdx.x;
    const int beg = scanM[bkt * NCH];
    const int end = (bkt + 1 < NB) ? scanM[(bkt + 1) * NCH] : E;

    hist[t] = 0;
    __syncthreads();
    for (int e = beg + t; e < end; e += 256)
        atomicAdd(&hist[((unsigned)ebuf[e]) >> 17], 1);
    __syncthreads();

    scn[t] = hist[t];
    __syncthreads();
    for (int off = 1; off < 256; off <<= 1) {
        int v = (t >= off) ? scn[t - off] : 0;
        __syncthreads();
        scn[t] += v;
        __syncthreads();
    }

    {
        int excl = scn[t] - hist[t];
        int rp = beg + excl;
        int node = (bkt << 8) + t;
        cur[t] = rp;
        if (node < N) {
            rowptr[node] = rp;
            dinv[node] = rsqrtf((float)(hist[t] + 1));   // +1 self loop
        }
    }
    if (bkt == NB - 1 && t == 0) rowptr[N] = E;
    __syncthreads();

    for (int e = beg + t; e < end; e += 256) {
        int pk = ebuf[e];
        int p = atomicAdd(&cur[((unsigned)pk) >> 17], 1);
        csr[p] = pk & 0x1FFFF;
    }
}

// ---- hs1(bf16) = (X @ W1) * dinv[row] via MFMA (W1t pre-converted bf16) ----
__global__ __launch_bounds__(256) void k_gemm1(const float* __restrict__ X,
                                               const unsigned short* __restrict__ W1t,
                                               const float* __restrict__ dinv,
                                               unsigned short* __restrict__ hs, int N) {
    __shared__ unsigned short Wl[64 * 72];   // Wt[n][k], stride 72
    __shared__ unsigned short Xs[64 * 72];   // Xs[r][k], stride 72
    const int t = threadIdx.x;
    const int row0 = blockIdx.x * 64;

    // stage W1t (bf16) into padded LDS: 512 uint4
#pragma unroll
    for (int i = 0; i < 2; ++i) {
        int idx = t + i * 256;               // uint4 index; covers n = idx>>3, k = (idx&7)*8
        int n = idx >> 3, k = (idx & 7) * 8;
        *(uint4*)&Wl[n * 72 + k] = ((const uint4*)W1t)[idx];
    }
    // stage X tile -> bf16
#pragma unroll
    for (int i = 0; i < 4; ++i) {
        int idx = t + i * 256;
        int r = idx >> 4, c = (idx & 15) * 4;
        int gr = row0 + r;
        float4 v = make_float4(0.f, 0.f, 0.f, 0.f);
        if (gr < N) v = *(const float4*)&X[(size_t)gr * F + c];
        unsigned p0 = (unsigned)f2bf(v.x) | ((unsigned)f2bf(v.y) << 16);
        unsigned p1 = (unsigned)f2bf(v.z) | ((unsigned)f2bf(v.w) << 16);
        *(uint2*)&Xs[r * 72 + c] = make_uint2(p0, p1);
    }
    __syncthreads();

    const int w    = t >> 6;
    const int lane = t & 63;
    const int l15  = lane & 15;
    const int quad = lane >> 4;

    bf16x8 bf[4][2];
#pragma unroll
    for (int ct = 0; ct < 4; ++ct)
#pragma unroll
        for (int kc = 0; kc < 2; ++kc)
            bf[ct][kc] = *(const bf16x8*)&Wl[(ct * 16 + l15) * 72 + kc * 32 + quad * 8];

    const int am = w * 16 + l15;
    bf16x8 af0 = *(const bf16x8*)&Xs[am * 72 + quad * 8];
    bf16x8 af1 = *(const bf16x8*)&Xs[am * 72 + 32 + quad * 8];

    f32x4 acc[4];
#pragma unroll
    for (int ct = 0; ct < 4; ++ct) {
        f32x4 z = {0.f, 0.f, 0.f, 0.f};
        z = __builtin_amdgcn_mfma_f32_16x16x32_bf16(af0, bf[ct][0], z, 0, 0, 0);
        z = __builtin_amdgcn_mfma_f32_16x16x32_bf16(af1, bf[ct][1], z, 0, 0, 0);
        acc[ct] = z;
    }

    float dv[4];
#pragma unroll
    for (int r = 0; r < 4; ++r) {
        int row = row0 + w * 16 + quad * 4 + r;
        dv[r] = (row < N) ? dinv[row] : 0.f;
    }
#pragma unroll
    for (int ct = 0; ct < 4; ++ct) {
#pragma unroll
        for (int r = 0; r < 4; ++r) {
            int row = row0 + w * 16 + quad * 4 + r;
            if (row < N)
                hs[(size_t)row * F + ct * 16 + l15] = f2bf(acc[ct][r] * dv[r]);
        }
    }
}

// ---- fused agg1 + gemm2: per-bucket gather -> relu(act1) in LDS -> @W2t -> hs2 ----
// 512 threads: phase1 = 64 nodes/iter x 4 iters (8 lanes/node); phase2 = 8 waves MFMA.
__global__ __launch_bounds__(512) void k_aggmm(const unsigned short* __restrict__ hs1,
                                               const int* __restrict__ rowptr,
                                               const int* __restrict__ csr,
                                               const unsigned short* __restrict__ W2t,
                                               const float* __restrict__ b1,
                                               unsigned short* __restrict__ hs2, int N) {
    __shared__ unsigned short Act[256 * 72];   // act1 bf16, stride 72 (36.9 KB)
    __shared__ unsigned short Wl[64 * 72];     // W2t padded (9.2 KB)
    __shared__ float sdv[256];                 // per-node dinv
    const int t = threadIdx.x;
    const int node0 = blockIdx.x << 8;

    // stage W2t
    if (t < 512) {
        int idx = t;                           // 512 uint4 = full 4096 bf16
        int n = idx >> 3, k = (idx & 7) * 8;
        *(uint4*)&Wl[n * 72 + k] = ((const uint4*)W2t)[idx];
    }

    const int lane = t & 7;
    const int nsub = t >> 3;                   // 0..63
    const uint4* hsb = (const uint4*)hs1;
    float4 bb0 = *(const float4*)&b1[lane * 8];
    float4 bb1 = *(const float4*)&b1[lane * 8 + 4];

#pragma unroll
    for (int it = 0; it < 4; ++it) {
        int local = it * 64 + nsub;
        int node = node0 + local;
        float sc = 0.f;
        unsigned p0 = 0, p1 = 0, p2 = 0, p3 = 0;
        if (node < N) {
            int beg = rowptr[node];
            int end = rowptr[node + 1];
            sc = rsqrtf((float)(end - beg + 1));
            float a0, a1, a2, a3, a4, a5, a6, a7;
            {
                uint4 u = hsb[(size_t)node * 8 + lane];   // self loop
                a0 = bflo(u.x); a1 = bfhi(u.x);
                a2 = bflo(u.y); a3 = bfhi(u.y);
                a4 = bflo(u.z); a5 = bfhi(u.z);
                a6 = bflo(u.w); a7 = bfhi(u.w);
            }
            for (int base = beg; base < end; base += 16) {
                int i0 = base + lane;
                int i1 = base + 8 + lane;
                int x0 = (i0 < end) ? csr[i0] : 0;
                int x1 = (i1 < end) ? csr[i1] : 0;
                uint4 r[16];
#pragma unroll
                for (int k = 0; k < 8; ++k) {
                    int s = __shfl(x0, k, 8);
                    r[k] = hsb[(size_t)s * 8 + lane];
                }
#pragma unroll
                for (int k = 0; k < 8; ++k) {
                    int s = __shfl(x1, k, 8);
                    r[8 + k] = hsb[(size_t)s * 8 + lane];
                }
                int cnt = min(16, end - base);
#pragma unroll
                for (int k = 0; k < 16; ++k) {
                    if (k < cnt) {
                        uint4 u = r[k];
                        a0 += bflo(u.x); a1 += bfhi(u.x);
                        a2 += bflo(u.y); a3 += bfhi(u.y);
                        a4 += bflo(u.z); a5 += bfhi(u.z);
                        a6 += bflo(u.w); a7 += bfhi(u.w);
                    }
                }
            }
            float o0 = fmaxf(a0 * sc + bb0.x, 0.f), o1 = fmaxf(a1 * sc + bb0.y, 0.f);
            float o2 = fmaxf(a2 * sc + bb0.z, 0.f), o3 = fmaxf(a3 * sc + bb0.w, 0.f);
            float o4 = fmaxf(a4 * sc + bb1.x, 0.f), o5 = fmaxf(a5 * sc + bb1.y, 0.f);
            float o6 = fmaxf(a6 * sc + bb1.z, 0.f), o7 = fmaxf(a7 * sc + bb1.w, 0.f);
            p0 = (unsigned)f2bf(o0) | ((unsigned)f2bf(o1) << 16);
            p1 = (unsigned)f2bf(o2) | ((unsigned)f2bf(o3) << 16);
            p2 = (unsigned)f2bf(o4) | ((unsigned)f2bf(o5) << 16);
            p3 = (unsigned)f2bf(o6) | ((unsigned)f2bf(o7) << 16);
        }
        *(uint4*)&Act[local * 72 + lane * 8] = make_uint4(p0, p1, p2, p3);
        if (lane == 0) sdv[local] = sc;
    }
    __syncthreads();

    // phase 2: act1(bucket) @ W2, scale by dinv, emit hs2
    const int w    = t >> 6;                   // 8 waves
    const int l    = t & 63;
    const int l15  = l & 15;
    const int quad = l >> 4;

    bf16x8 bf[4][2];
#pragma unroll
    for (int nt = 0; nt < 4; ++nt)
#pragma unroll
        for (int kc = 0; kc < 2; ++kc)
            bf[nt][kc] = *(const bf16x8*)&Wl[(nt * 16 + l15) * 72 + kc * 32 + quad * 8];

#pragma unroll
    for (int mt = 0; mt < 2; ++mt) {
        int m0 = w * 32 + mt * 16;
        bf16x8 af0 = *(const bf16x8*)&Act[(m0 + l15) * 72 + quad * 8];
        bf16x8 af1 = *(const bf16x8*)&Act[(m0 + l15) * 72 + 32 + quad * 8];
#pragma unroll
        for (int nt = 0; nt < 4; ++nt) {
            f32x4 z = {0.f, 0.f, 0.f, 0.f};
            z = __builtin_amdgcn_mfma_f32_16x16x32_bf16(af0, bf[nt][0], z, 0, 0, 0);
            z = __builtin_amdgcn_mfma_f32_16x16x32_bf16(af1, bf[nt][1], z, 0, 0, 0);
#pragma unroll
            for (int r = 0; r < 4; ++r) {
                int row = m0 + quad * 4 + r;
                int node = node0 + row;
                if (node < N)
                    hs2[(size_t)node * F + nt * 16 + l15] = f2bf(z[r] * sdv[row]);
            }
        }
    }
}

// ---- final aggregate (layer 2): gather hs2, epilogue to out ----
__global__ __launch_bounds__(256) void k_agg(const unsigned short* __restrict__ hs,
                                             const int* __restrict__ rowptr,
                                             const int* __restrict__ csr,
                                             const float* __restrict__ dinv,
                                             const float* __restrict__ b,
                                             float* __restrict__ out, int N) {
    int gid = blockIdx.x * 256 + threadIdx.x;
    int node = gid >> 3;
    int lane = gid & 7;
    if (node >= N) return;
    int beg = rowptr[node];
    int end = rowptr[node + 1];
    const int q = lane * 8;
    const uint4* hsb = (const uint4*)hs;

    float acc0, acc1, acc2, acc3, acc4, acc5, acc6, acc7;
    {
        uint4 u = hsb[(size_t)node * 8 + lane];   // self loop
        acc0 = bflo(u.x); acc1 = bfhi(u.x);
        acc2 = bflo(u.y); acc3 = bfhi(u.y);
        acc4 = bflo(u.z); acc5 = bfhi(u.z);
        acc6 = bflo(u.w); acc7 = bfhi(u.w);
    }
    for (int base = beg; base < end; base += 16) {
        int i0 = base + lane;
        int i1 = base + 8 + lane;
        int x0 = (i0 < end) ? csr[i0] : 0;
        int x1 = (i1 < end) ? csr[i1] : 0;
        uint4 r[16];
#pragma unroll
        for (int k = 0; k < 8; ++k) {
            int s = __shfl(x0, k, 8);
            r[k] = hsb[(size_t)s * 8 + lane];
        }
#pragma unroll
        for (int k = 0; k < 8; ++k) {
            int s = __shfl(x1, k, 8);
            r[8 + k] = hsb[(size_t)s * 8 + lane];
        }
        int cnt = min(16, end - base);
#pragma unroll
        for (int k = 0; k < 16; ++k) {
            if (k < cnt) {
                uint4 u = r[k];
                acc0 += bflo(u.x); acc1 += bfhi(u.x);
                acc2 += bflo(u.y); acc3 += bfhi(u.y);
                acc4 += bflo(u.z); acc5 += bfhi(u.z);
                acc6 += bflo(u.w); acc7 += bfhi(u.w);
            }
        }
    }

    float sc = dinv[node];
    float4 b0 = *(const float4*)&b[q];
    float4 b1 = *(const float4*)&b[q + 4];
    float4 o0 = make_float4(acc0 * sc + b0.x, acc1 * sc + b0.y,
                            acc2 * sc + b0.z, acc3 * sc + b0.w);
    float4 o1 = make_float4(acc4 * sc + b1.x, acc5 * sc + b1.y,
                            acc6 * sc + b1.z, acc7 * sc + b1.w);
    *(float4*)&out[(size_t)node * F + q] = o0;
    *(float4*)&out[(size_t)node * F + q + 4] = o1;
}

extern "C" void kernel_launch(void* const* d_in, const int* in_sizes, int n_in,
                              void* d_out, int out_size, void* d_ws, size_t ws_size,
                              hipStream_t stream) {
    const float* x  = (const float*)d_in[0];
    const int*   ei = (const int*)d_in[1];
    const float* W1 = (const float*)d_in[2];
    const float* b1 = (const float*)d_in[3];
    const float* W2 = (const float*)d_in[4];
    const float* b2 = (const float*)d_in[5];
    float* out = (float*)d_out;

    const int N = in_sizes[0] / F;
    const int E = in_sizes[1] / 2;
    const int* src = ei;
    const int* dst = ei + E;

    const int NB = (N + 255) >> 8;                       // buckets (391)
    const int chunk = (E + NCH - 1) / NCH;
    const int M  = NB * NCH;
    const int Mp = ((M + 1023) / 1024) * 1024;
    const int nb2 = Mp / 1024;                           // <= 256

    // ws: W1t | W2t | dinv | part2 | rowptr | histM | ebuf | csr | hs1 | hs2
    char* ws = (char*)d_ws;
    size_t a = 0;
    unsigned short* W1t = (unsigned short*)(ws + a); a += (4096 * 2 + 255) & ~(size_t)255;
    unsigned short* W2t = (unsigned short*)(ws + a); a += (4096 * 2 + 255) & ~(size_t)255;
    float* dinv   = (float*)(ws + a); a += ((size_t)N * 4 + 255) & ~(size_t)255;
    int*   part2  = (int*)(ws + a);   a += ((size_t)nb2 * 4 + 255) & ~(size_t)255;
    int*   rowptr = (int*)(ws + a);   a += ((size_t)(N + 1) * 4 + 255) & ~(size_t)255;
    int*   histM  = (int*)(ws + a);   a += ((size_t)Mp * 4 + 255) & ~(size_t)255;
    int*   ebuf   = (int*)(ws + a);   a += ((size_t)E * 4 + 255) & ~(size_t)255;
    int*   csr    = (int*)(ws + a);   a += ((size_t)E * 4 + 255) & ~(size_t)255;
    unsigned short* hs1 = (unsigned short*)(ws + a); a += ((size_t)N * F * 2 + 255) & ~(size_t)255;
    unsigned short* hs2 = (unsigned short*)(ws + a);

    const size_t ldsNB = (size_t)NB * 4;
    const int gGemm = (N + 63) / 64;
    const int gAgg  = (int)(((long long)N * 8 + 255) / 256);

    // ---- weight prep + CSR build ----
    k_prep<<<2, 256, 0, stream>>>(W1, W2, W1t, W2t);
    hipMemsetAsync(histM, 0, (size_t)Mp * 4, stream);
    k_hist<<<NCH, 256, ldsNB, stream>>>(dst, histM, E, chunk, NB);
    s_part<<<nb2, 256, 0, stream>>>(histM, part2, Mp);
    s_scanp<<<1, 256, 0, stream>>>(part2, nb2);
    s_emit<<<nb2, 256, 0, stream>>>(histM, part2, Mp);
    k_scatter2<<<NCH, 256, ldsNB, stream>>>(src, dst, histM, ebuf, E, chunk, NB);
    k_csr<<<NB, 256, 0, stream>>>(ebuf, histM, rowptr, csr, dinv, N, E, NB);

    // ---- layer 1 GEMM, fused agg1+gemm2, layer 2 agg ----
    k_gemm1<<<gGemm, 256, 0, stream>>>(x, W1t, dinv, hs1, N);
    k_aggmm<<<NB, 512, 0, stream>>>(hs1, rowptr, csr, W2t, b1, hs2, N);
    k_agg<<<gAgg, 256, 0, stream>>>(hs2, rowptr, csr, dinv, b2, out, N);
}

// Round 10
// 190.635 us; speedup vs baseline: 5.4935x; 1.0402x over previous
//
#include <hip/hip_runtime.h>

#define F 64
#define NCH 256          // edge chunks (= blocks) for hist/scatter passes
// buckets are 256 nodes wide: bucket = dst >> 8. N=100000 -> NB=391
// packing: ebuf entry = src | (dst&255)<<17  (needs N < 131072)

typedef __attribute__((ext_vector_type(8))) short bf16x8;
typedef __attribute__((ext_vector_type(4))) float f32x4;

static __device__ __forceinline__ unsigned short f2bf(float f) {
    unsigned u = __float_as_uint(f);
    return (unsigned short)((u + 0x7fffu + ((u >> 16) & 1u)) >> 16);   // RNE
}
static __device__ __forceinline__ float bflo(unsigned u) { return __uint_as_float(u << 16); }
static __device__ __forceinline__ float bfhi(unsigned u) { return __uint_as_float(u & 0xffff0000u); }

// ---- pass A: per-chunk bucket histogram (blocks 0..NCH-1) + weight prep (last 2 blocks) ----
__global__ __launch_bounds__(256) void k_histprep(const int* __restrict__ dst,
                                                  int* __restrict__ histM,
                                                  const float* __restrict__ W1,
                                                  const float* __restrict__ W2,
                                                  unsigned short* __restrict__ W1t,
                                                  unsigned short* __restrict__ W2t,
                                                  int E, int chunk, int NB) {
    const int t = threadIdx.x;
    if (blockIdx.x >= NCH) {                 // weight prep: W -> bf16 transposed [n*64+k]
        int which = blockIdx.x - NCH;
        const float* W = which ? W2 : W1;
        unsigned short* Wt = which ? W2t : W1t;
#pragma unroll
        for (int i = 0; i < 16; ++i) {
            int e = t + i * 256;
            int n = e >> 6, k = e & 63;
            Wt[e] = f2bf(W[k * 64 + n]);
        }
        return;
    }
    extern __shared__ int h[];
    for (int i = t; i < NB; i += 256) h[i] = 0;
    __syncthreads();
    const int lo = blockIdx.x * chunk;
    const int hi = min(E, lo + chunk);
    for (int e = lo + t; e < hi; e += 256) {
        atomicAdd(&h[dst[e] >> 8], 1);
    }
    __syncthreads();
    for (int i = t; i < NB; i += 256) histM[i * NCH + blockIdx.x] = h[i];
}

// ---- 3-stage exclusive scan over M ints (tail [M,ceil1024) treated as 0) ----
__global__ __launch_bounds__(256) void s_part(const int* __restrict__ v,
                                              int* __restrict__ part, int M) {
    __shared__ int sd[256];
    const int t = threadIdx.x;
    const int base = blockIdx.x * 1024 + t * 4;
    int s = 0;
    if (base + 3 < M) {
        int4 d = *(const int4*)&v[base];
        s = d.x + d.y + d.z + d.w;
    } else {
#pragma unroll
        for (int j = 0; j < 4; ++j) if (base + j < M) s += v[base + j];
    }
    sd[t] = s;
    __syncthreads();
    for (int off = 128; off > 0; off >>= 1) {
        if (t < off) sd[t] += sd[t + off];
        __syncthreads();
    }
    if (t == 0) part[blockIdx.x] = sd[0];
}

__global__ __launch_bounds__(256) void s_scanp(int* __restrict__ part, int nb) {
    __shared__ int sums[256];
    const int t = threadIdx.x;
    int s = (t < nb) ? part[t] : 0;          // nb <= 256
    sums[t] = s;
    __syncthreads();
    for (int off = 1; off < 256; off <<= 1) {
        int v = (t >= off) ? sums[t - off] : 0;
        __syncthreads();
        sums[t] += v;
        __syncthreads();
    }
    if (t < nb) part[t] = sums[t] - s;       // exclusive
}

__global__ __launch_bounds__(256) void s_emit(int* __restrict__ v,
                                              const int* __restrict__ part, int M) {
    __shared__ int sums[256];
    const int t = threadIdx.x;
    const int base = blockIdx.x * 1024 + t * 4;
    int d0 = 0, d1 = 0, d2 = 0, d3 = 0;
    if (base + 3 < M) {
        int4 d = *(const int4*)&v[base];
        d0 = d.x; d1 = d.y; d2 = d.z; d3 = d.w;
    } else {
        if (base + 0 < M) d0 = v[base + 0];
        if (base + 1 < M) d1 = v[base + 1];
        if (base + 2 < M) d2 = v[base + 2];
        if (base + 3 < M) d3 = v[base + 3];
    }
    int tot = d0 + d1 + d2 + d3;
    sums[t] = tot;
    __syncthreads();
    for (int off = 1; off < 256; off <<= 1) {
        int x = (t >= off) ? sums[t - off] : 0;
        __syncthreads();
        sums[t] += x;
        __syncthreads();
    }
    int o0 = part[blockIdx.x] + sums[t] - tot;
    int e0 = o0, e1 = o0 + d0, e2 = e1 + d1, e3 = e2 + d2;
    if (base + 3 < M) {
        *(int4*)&v[base] = make_int4(e0, e1, e2, e3);
    } else {
        int ee[4] = {e0, e1, e2, e3};
        for (int j = 0; j < 4; ++j) if (base + j < M) v[base + j] = ee[j];
    }
}

// ---- pass C: scatter packed edges into per-(bucket,block)-private regions ----
__global__ __launch_bounds__(256) void k_scatter2(const int* __restrict__ src,
                                                  const int* __restrict__ dst,
                                                  const int* __restrict__ scanM,
                                                  int* __restrict__ ebuf,
                                                  int E, int chunk, int NB) {
    extern __shared__ int cur[];
    const int t = threadIdx.x;
    for (int i = t; i < NB; i += 256) cur[i] = scanM[i * NCH + blockIdx.x];
    __syncthreads();
    const int lo = blockIdx.x * chunk;
    const int hi = min(E, lo + chunk);
    for (int e = lo + t; e < hi; e += 256) {
        int s = src[e];
        int d = dst[e];
        int p = atomicAdd(&cur[d >> 8], 1);
        ebuf[p] = s | ((d & 255) << 17);
    }
}

// ---- pass D: per-bucket LDS counting sort -> rowptr, dinv, node-sorted csr ----
__global__ __launch_bounds__(256) void k_csr(const int* __restrict__ ebuf,
                                             const int* __restrict__ scanM,
                                             int* __restrict__ rowptr,
                                             int* __restrict__ csr,
                                             float* __restrict__ dinv,
                                             int N, int E, int NB) {
    __shared__ int hist[256];
    __shared__ int scn[256];
    __shared__ int cur[256];
    const int t = threadIdx.x;
    const int bkt = blockIdx.x;
    const int beg = scanM[bkt * NCH];
    const int end = (bkt + 1 < NB) ? scanM[(bkt + 1) * NCH] : E;

    hist[t] = 0;
    __syncthreads();
    for (int e = beg + t; e < end; e += 256)
        atomicAdd(&hist[((unsigned)ebuf[e]) >> 17], 1);
    __syncthreads();

    scn[t] = hist[t];
    __syncthreads();
    for (int off = 1; off < 256; off <<= 1) {
        int v = (t >= off) ? scn[t - off] : 0;
        __syncthreads();
        scn[t] += v;
        __syncthreads();
    }

    {
        int excl = scn[t] - hist[t];
        int rp = beg + excl;
        int node = (bkt << 8) + t;
        cur[t] = rp;
        if (node < N) {
            rowptr[node] = rp;
            dinv[node] = rsqrtf((float)(hist[t] + 1));   // +1 self loop
        }
    }
    if (bkt == NB - 1 && t == 0) rowptr[N] = E;
    __syncthreads();

    for (int e = beg + t; e < end; e += 256) {
        int pk = ebuf[e];
        int p = atomicAdd(&cur[((unsigned)pk) >> 17], 1);
        csr[p] = pk & 0x1FFFF;
    }
}

// ---- hs1(bf16) = (X @ W1) * dinv[row] via MFMA (W1t pre-converted bf16) ----
__global__ __launch_bounds__(256) void k_gemm1(const float* __restrict__ X,
                                               const unsigned short* __restrict__ W1t,
                                               const float* __restrict__ dinv,
                                               unsigned short* __restrict__ hs, int N) {
    __shared__ unsigned short Wl[64 * 72];   // Wt[n][k], stride 72
    __shared__ unsigned short Xs[64 * 72];   // Xs[r][k], stride 72
    const int t = threadIdx.x;
    const int row0 = blockIdx.x * 64;

#pragma unroll
    for (int i = 0; i < 2; ++i) {
        int idx = t + i * 256;
        int n = idx >> 3, k = (idx & 7) * 8;
        *(uint4*)&Wl[n * 72 + k] = ((const uint4*)W1t)[idx];
    }
#pragma unroll
    for (int i = 0; i < 4; ++i) {
        int idx = t + i * 256;
        int r = idx >> 4, c = (idx & 15) * 4;
        int gr = row0 + r;
        float4 v = make_float4(0.f, 0.f, 0.f, 0.f);
        if (gr < N) v = *(const float4*)&X[(size_t)gr * F + c];
        unsigned p0 = (unsigned)f2bf(v.x) | ((unsigned)f2bf(v.y) << 16);
        unsigned p1 = (unsigned)f2bf(v.z) | ((unsigned)f2bf(v.w) << 16);
        *(uint2*)&Xs[r * 72 + c] = make_uint2(p0, p1);
    }
    __syncthreads();

    const int w    = t >> 6;
    const int lane = t & 63;
    const int l15  = lane & 15;
    const int quad = lane >> 4;

    bf16x8 bf[4][2];
#pragma unroll
    for (int ct = 0; ct < 4; ++ct)
#pragma unroll
        for (int kc = 0; kc < 2; ++kc)
            bf[ct][kc] = *(const bf16x8*)&Wl[(ct * 16 + l15) * 72 + kc * 32 + quad * 8];

    const int am = w * 16 + l15;
    bf16x8 af0 = *(const bf16x8*)&Xs[am * 72 + quad * 8];
    bf16x8 af1 = *(const bf16x8*)&Xs[am * 72 + 32 + quad * 8];

    f32x4 acc[4];
#pragma unroll
    for (int ct = 0; ct < 4; ++ct) {
        f32x4 z = {0.f, 0.f, 0.f, 0.f};
        z = __builtin_amdgcn_mfma_f32_16x16x32_bf16(af0, bf[ct][0], z, 0, 0, 0);
        z = __builtin_amdgcn_mfma_f32_16x16x32_bf16(af1, bf[ct][1], z, 0, 0, 0);
        acc[ct] = z;
    }

    float dv[4];
#pragma unroll
    for (int r = 0; r < 4; ++r) {
        int row = row0 + w * 16 + quad * 4 + r;
        dv[r] = (row < N) ? dinv[row] : 0.f;
    }
#pragma unroll
    for (int ct = 0; ct < 4; ++ct) {
#pragma unroll
        for (int r = 0; r < 4; ++r) {
            int row = row0 + w * 16 + quad * 4 + r;
            if (row < N)
                hs[(size_t)row * F + ct * 16 + l15] = f2bf(acc[ct][r] * dv[r]);
        }
    }
}

// ---- fused agg1 + gemm2: per-bucket gather -> relu(act1) in LDS -> @W2t -> hs2 ----
// hs2 emitted in SLICED layout: hs2[(slice*N + node)*16 + pos], slice=feature>>4.
__global__ __launch_bounds__(512) void k_aggmm(const unsigned short* __restrict__ hs1,
                                               const int* __restrict__ rowptr,
                                               const int* __restrict__ csr,
                                               const unsigned short* __restrict__ W2t,
                                               const float* __restrict__ b1,
                                               unsigned short* __restrict__ hs2, int N) {
    __shared__ unsigned short Act[256 * 72];   // act1 bf16, stride 72
    __shared__ unsigned short Wl[64 * 72];     // W2t padded
    __shared__ float sdv[256];                 // per-node dinv
    const int t = threadIdx.x;
    const int node0 = blockIdx.x << 8;

    {
        int idx = t;                           // 512 uint4 = full 4096 bf16
        int n = idx >> 3, k = (idx & 7) * 8;
        *(uint4*)&Wl[n * 72 + k] = ((const uint4*)W2t)[idx];
    }

    const int lane = t & 7;
    const int nsub = t >> 3;                   // 0..63
    const uint4* hsb = (const uint4*)hs1;
    float4 bb0 = *(const float4*)&b1[lane * 8];
    float4 bb1 = *(const float4*)&b1[lane * 8 + 4];

#pragma unroll
    for (int it = 0; it < 4; ++it) {
        int local = it * 64 + nsub;
        int node = node0 + local;
        float sc = 0.f;
        unsigned p0 = 0, p1 = 0, p2 = 0, p3 = 0;
        if (node < N) {
            int beg = rowptr[node];
            int end = rowptr[node + 1];
            sc = rsqrtf((float)(end - beg + 1));
            float a0, a1, a2, a3, a4, a5, a6, a7;
            {
                uint4 u = hsb[(size_t)node * 8 + lane];   // self loop
                a0 = bflo(u.x); a1 = bfhi(u.x);
                a2 = bflo(u.y); a3 = bfhi(u.y);
                a4 = bflo(u.z); a5 = bfhi(u.z);
                a6 = bflo(u.w); a7 = bfhi(u.w);
            }
            for (int base = beg; base < end; base += 16) {
                int i0 = base + lane;
                int i1 = base + 8 + lane;
                int x0 = (i0 < end) ? csr[i0] : 0;
                int x1 = (i1 < end) ? csr[i1] : 0;
                uint4 r[16];
#pragma unroll
                for (int k = 0; k < 8; ++k) {
                    int s = __shfl(x0, k, 8);
                    r[k] = hsb[(size_t)s * 8 + lane];
                }
#pragma unroll
                for (int k = 0; k < 8; ++k) {
                    int s = __shfl(x1, k, 8);
                    r[8 + k] = hsb[(size_t)s * 8 + lane];
                }
                int cnt = min(16, end - base);
#pragma unroll
                for (int k = 0; k < 16; ++k) {
                    if (k < cnt) {
                        uint4 u = r[k];
                        a0 += bflo(u.x); a1 += bfhi(u.x);
                        a2 += bflo(u.y); a3 += bfhi(u.y);
                        a4 += bflo(u.z); a5 += bfhi(u.z);
                        a6 += bflo(u.w); a7 += bfhi(u.w);
                    }
                }
            }
            float o0 = fmaxf(a0 * sc + bb0.x, 0.f), o1 = fmaxf(a1 * sc + bb0.y, 0.f);
            float o2 = fmaxf(a2 * sc + bb0.z, 0.f), o3 = fmaxf(a3 * sc + bb0.w, 0.f);
            float o4 = fmaxf(a4 * sc + bb1.x, 0.f), o5 = fmaxf(a5 * sc + bb1.y, 0.f);
            float o6 = fmaxf(a6 * sc + bb1.z, 0.f), o7 = fmaxf(a7 * sc + bb1.w, 0.f);
            p0 = (unsigned)f2bf(o0) | ((unsigned)f2bf(o1) << 16);
            p1 = (unsigned)f2bf(o2) | ((unsigned)f2bf(o3) << 16);
            p2 = (unsigned)f2bf(o4) | ((unsigned)f2bf(o5) << 16);
            p3 = (unsigned)f2bf(o6) | ((unsigned)f2bf(o7) << 16);
        }
        *(uint4*)&Act[local * 72 + lane * 8] = make_uint4(p0, p1, p2, p3);
        if (lane == 0) sdv[local] = sc;
    }
    __syncthreads();

    // phase 2: act1(bucket) @ W2, scale by dinv, emit hs2 (sliced layout)
    const int w    = t >> 6;                   // 8 waves
    const int l    = t & 63;
    const int l15  = l & 15;
    const int quad = l >> 4;

    bf16x8 bf[4][2];
#pragma unroll
    for (int nt = 0; nt < 4; ++nt)
#pragma unroll
        for (int kc = 0; kc < 2; ++kc)
            bf[nt][kc] = *(const bf16x8*)&Wl[(nt * 16 + l15) * 72 + kc * 32 + quad * 8];

#pragma unroll
    for (int mt = 0; mt < 2; ++mt) {
        int m0 = w * 32 + mt * 16;
        bf16x8 af0 = *(const bf16x8*)&Act[(m0 + l15) * 72 + quad * 8];
        bf16x8 af1 = *(const bf16x8*)&Act[(m0 + l15) * 72 + 32 + quad * 8];
#pragma unroll
        for (int nt = 0; nt < 4; ++nt) {
            f32x4 z = {0.f, 0.f, 0.f, 0.f};
            z = __builtin_amdgcn_mfma_f32_16x16x32_bf16(af0, bf[nt][0], z, 0, 0, 0);
            z = __builtin_amdgcn_mfma_f32_16x16x32_bf16(af1, bf[nt][1], z, 0, 0, 0);
#pragma unroll
            for (int r = 0; r < 4; ++r) {
                int row = m0 + quad * 4 + r;
                int node = node0 + row;
                if (node < N)
                    hs2[((size_t)nt * N + node) * 16 + l15] = f2bf(z[r] * sdv[row]);
            }
        }
    }
}

// ---- final aggregate, feature-sliced for XCD-L2 confinement ----
// slice = blockIdx&3 (== XCD mod 4 under round-robin mapping); panel 3.2MB < 4MB L2.
// 2 lanes/node, 128 nodes/block; 1-round shuffle reduce.
__global__ __launch_bounds__(256) void k_agg2(const unsigned short* __restrict__ hs2,
                                              const int* __restrict__ rowptr,
                                              const int* __restrict__ csr,
                                              const float* __restrict__ dinv,
                                              const float* __restrict__ b,
                                              float* __restrict__ out, int N) {
    const int slice = blockIdx.x & 3;
    const int chunk = blockIdx.x >> 2;
    const int t = threadIdx.x;
    const int node = chunk * 128 + (t >> 1);
    const int lane = t & 1;
    if (node >= N) return;
    const int beg = rowptr[node];
    const int end = rowptr[node + 1];
    const unsigned short* hp = hs2 + (size_t)slice * N * 16;

    float a[16];
#pragma unroll
    for (int j = 0; j < 16; ++j) a[j] = 0.f;

    for (int e = beg + lane; e < end; e += 2) {
        int s = csr[e];
        const uint4* p = (const uint4*)(hp + (size_t)s * 16);
        uint4 u0 = p[0];
        uint4 u1 = p[1];
        a[0] += bflo(u0.x); a[1] += bfhi(u0.x);
        a[2] += bflo(u0.y); a[3] += bfhi(u0.y);
        a[4] += bflo(u0.z); a[5] += bfhi(u0.z);
        a[6] += bflo(u0.w); a[7] += bfhi(u0.w);
        a[8]  += bflo(u1.x); a[9]  += bfhi(u1.x);
        a[10] += bflo(u1.y); a[11] += bfhi(u1.y);
        a[12] += bflo(u1.z); a[13] += bfhi(u1.z);
        a[14] += bflo(u1.w); a[15] += bfhi(u1.w);
    }
#pragma unroll
    for (int j = 0; j < 16; ++j) a[j] += __shfl_xor(a[j], 1, 2);

    const float sc = dinv[node];
    const int j0 = lane * 8;                   // this lane writes features j0..j0+7
    uint4 sv = *(const uint4*)(hp + (size_t)node * 16 + j0);   // self loop
    float s0 = bflo(sv.x), s1 = bfhi(sv.x), s2 = bflo(sv.y), s3 = bfhi(sv.y);
    float s4 = bflo(sv.z), s5 = bfhi(sv.z), s6 = bflo(sv.w), s7 = bfhi(sv.w);
    float4 bb0 = *(const float4*)&b[slice * 16 + j0];
    float4 bb1 = *(const float4*)&b[slice * 16 + j0 + 4];
    float4 o0 = make_float4((a[j0 + 0] + s0) * sc + bb0.x,
                            (a[j0 + 1] + s1) * sc + bb0.y,
                            (a[j0 + 2] + s2) * sc + bb0.z,
                            (a[j0 + 3] + s3) * sc + bb0.w);
    float4 o1 = make_float4((a[j0 + 4] + s4) * sc + bb1.x,
                            (a[j0 + 5] + s5) * sc + bb1.y,
                            (a[j0 + 6] + s6) * sc + bb1.z,
                            (a[j0 + 7] + s7) * sc + bb1.w);
    float* op = &out[(size_t)node * F + slice * 16 + j0];
    *(float4*)op = o0;
    *(float4*)(op + 4) = o1;
}

extern "C" void kernel_launch(void* const* d_in, const int* in_sizes, int n_in,
                              void* d_out, int out_size, void* d_ws, size_t ws_size,
                              hipStream_t stream) {
    const float* x  = (const float*)d_in[0];
    const int*   ei = (const int*)d_in[1];
    const float* W1 = (const float*)d_in[2];
    const float* b1 = (const float*)d_in[3];
    const float* W2 = (const float*)d_in[4];
    const float* b2 = (const float*)d_in[5];
    float* out = (float*)d_out;

    const int N = in_sizes[0] / F;
    const int E = in_sizes[1] / 2;
    const int* src = ei;
    const int* dst = ei + E;

    const int NB = (N + 255) >> 8;                       // buckets (391)
    const int chunk = (E + NCH - 1) / NCH;
    const int M  = NB * NCH;
    const int Mp = ((M + 1023) / 1024) * 1024;
    const int nb2 = Mp / 1024;                           // <= 256

    // ws: W1t | W2t | dinv | part2 | rowptr | histM | ebuf | csr | hs1 | hs2
    char* ws = (char*)d_ws;
    size_t a = 0;
    unsigned short* W1t = (unsigned short*)(ws + a); a += (4096 * 2 + 255) & ~(size_t)255;
    unsigned short* W2t = (unsigned short*)(ws + a); a += (4096 * 2 + 255) & ~(size_t)255;
    float* dinv   = (float*)(ws + a); a += ((size_t)N * 4 + 255) & ~(size_t)255;
    int*   part2  = (int*)(ws + a);   a += ((size_t)nb2 * 4 + 255) & ~(size_t)255;
    int*   rowptr = (int*)(ws + a);   a += ((size_t)(N + 1) * 4 + 255) & ~(size_t)255;
    int*   histM  = (int*)(ws + a);   a += ((size_t)Mp * 4 + 255) & ~(size_t)255;
    int*   ebuf   = (int*)(ws + a);   a += ((size_t)E * 4 + 255) & ~(size_t)255;
    int*   csr    = (int*)(ws + a);   a += ((size_t)E * 4 + 255) & ~(size_t)255;
    unsigned short* hs1 = (unsigned short*)(ws + a); a += ((size_t)N * F * 2 + 255) & ~(size_t)255;
    unsigned short* hs2 = (unsigned short*)(ws + a);

    const size_t ldsNB = (size_t)NB * 4;
    const int gGemm = (N + 63) / 64;
    const int gAgg2 = ((N + 127) / 128) * 4;             // 4 slices

    // ---- CSR build (hist fused with weight prep; no memset — scan guards tail) ----
    k_histprep<<<NCH + 2, 256, ldsNB, stream>>>(dst, histM, W1, W2, W1t, W2t, E, chunk, NB);
    s_part<<<nb2, 256, 0, stream>>>(histM, part2, M);
    s_scanp<<<1, 256, 0, stream>>>(part2, nb2);
    s_emit<<<nb2, 256, 0, stream>>>(histM, part2, M);
    k_scatter2<<<NCH, 256, ldsNB, stream>>>(src, dst, histM, ebuf, E, chunk, NB);
    k_csr<<<NB, 256, 0, stream>>>(ebuf, histM, rowptr, csr, dinv, N, E, NB);

    // ---- layer 1 GEMM, fused agg1+gemm2, sliced final agg ----
    k_gemm1<<<gGemm, 256, 0, stream>>>(x, W1t, dinv, hs1, N);
    k_aggmm<<<NB, 512, 0, stream>>>(hs1, rowptr, csr, W2t, b1, hs2, N);
    k_agg2<<<gAgg2, 256, 0, stream>>>(hs2, rowptr, csr, dinv, b2, out, N);
}